// Round 1
// baseline (4105.701 us; speedup 1.0000x reference)
//
#include <hip/hip_runtime.h>

// ---------------------------------------------------------------------------
// VQ-VAE forward (fp32). All matmul-shaped work expressed as tiled GEMMs:
//   conv/deconv/proj: OUT[co,t] = sum_{K'=(ci,k)} W[co,K'] * IM[K',t]
//   VQ:               argmin_k ( |e_k|^2 - 2 z.e_k )
// No fp32 MFMA on CDNA4 -> vector-ALU FMA kernels.
// Precision: |e_k|^2 in fp64 (single fp32 round at store), dots fp32
// sequential, argmin first-k tie-break -> matches numpy argmin.
// ---------------------------------------------------------------------------

struct CP {
  const float* in; const float* w; const float* bias; float* out;
  const int* vidx; const float* emb;
  int Ci, Ti, Co, To, KW, K2, stride, pad;
};

// Tiled conv/deconv GEMM. Block: 128 threads = 16 tx (t) x 8 ty (co).
// Block tile 128 t x 64 co, thread tile 8t x 8co, K' chunks of 64.
// LDS: IM [64kk][128t] (conflict-free rows), WT [64kk][65] (pad -> spread banks).
template<bool DECONV, bool IN_NTC, bool OUT_NTC, bool RELU, bool IN_EMB>
__global__ __launch_bounds__(128) void conv_kernel(CP p) {
  __shared__ float IMs[64 * 128];
  __shared__ float WTs[64 * 65];
  const int tid = threadIdx.x;
  const int tx = tid & 15, ty = tid >> 4;
  const int b = blockIdx.z;
  const int tbase = blockIdx.x * 128;
  const int cobase = blockIdx.y * 64;
  float acc[8][8];
#pragma unroll
  for (int i = 0; i < 8; ++i) {
#pragma unroll
    for (int j = 0; j < 8; ++j) acc[i][j] = 0.f;
  }
  const int nch = (p.K2 + 63) >> 6;
  for (int ch = 0; ch < nch; ++ch) {
    const int kbase = ch << 6;
    __syncthreads();
    // stage W transposed: WT[kk][co], global reads coalesced along kk
#pragma unroll 4
    for (int i = 0; i < 32; ++i) {
      const int e = i * 128 + tid;
      const int kk = e & 63, co = e >> 6;
      const int kg = kbase + kk, cog = cobase + co;
      float v = 0.f;
      if (kg < p.K2 && cog < p.Co) v = p.w[cog * p.K2 + kg];
      WTs[kk * 65 + co] = v;
    }
    // stage IM[kk][t] with per-layer gather (zero-fill invalid taps)
#pragma unroll 2
    for (int i = 0; i < 64; ++i) {
      const int e = i * 128 + tid;
      const int tl = e & 127, kk = e >> 7;
      const int kg = kbase + kk;
      const int t = tbase + tl;
      float v = 0.f;
      if (kg < p.K2 && t < p.To) {
        int ci, k;
        if (p.KW == 3) { ci = kg / 3; k = kg - ci * 3; } else { ci = kg; k = 0; }
        int tin; bool ok;
        if (DECONV) {
          // ConvTranspose(k=3,s=2,p=1,op=1) == lhs-dilated conv, pad (1,2):
          // tap valid iff (t+k-1) even and (t+k-1)/2 in [0,Ti)
          const int a = t + k - 1;
          tin = a >> 1;
          ok = (a >= 0) && ((a & 1) == 0) && (tin < p.Ti);
        } else {
          tin = t * p.stride + k - p.pad;
          ok = (tin >= 0) && (tin < p.Ti);
        }
        if (ok) {
          if (IN_EMB)      v = p.emb[p.vidx[b * p.Ti + tin] * 256 + ci]; // z_q gather
          else if (IN_NTC) v = p.in[(b * p.Ti + tin) * p.Ci + ci];
          else             v = p.in[(b * p.Ci + ci) * p.Ti + tin];
        }
      }
      IMs[kk * 128 + tl] = v;
    }
    __syncthreads();
#pragma unroll 4
    for (int kk = 0; kk < 64; ++kk) {
      const float4 x0 = *(const float4*)&IMs[kk * 128 + tx * 4];
      const float4 x1 = *(const float4*)&IMs[kk * 128 + tx * 4 + 64];
#pragma unroll
      for (int cc = 0; cc < 8; ++cc) {
        const float wv = WTs[kk * 65 + ty * 8 + cc];
        acc[0][cc] = fmaf(x0.x, wv, acc[0][cc]);
        acc[1][cc] = fmaf(x0.y, wv, acc[1][cc]);
        acc[2][cc] = fmaf(x0.z, wv, acc[2][cc]);
        acc[3][cc] = fmaf(x0.w, wv, acc[3][cc]);
        acc[4][cc] = fmaf(x1.x, wv, acc[4][cc]);
        acc[5][cc] = fmaf(x1.y, wv, acc[5][cc]);
        acc[6][cc] = fmaf(x1.z, wv, acc[6][cc]);
        acc[7][cc] = fmaf(x1.w, wv, acc[7][cc]);
      }
    }
  }
  // epilogue: bias (+relu), NCT float4 stores or NTC scalar (final transpose)
#pragma unroll
  for (int cc = 0; cc < 8; ++cc) {
    const int co = cobase + ty * 8 + cc;
    if (co < p.Co) {
      const float bv = p.bias[co];
#pragma unroll
      for (int g = 0; g < 2; ++g) {
        const int t0 = tbase + tx * 4 + g * 64;
        if (t0 < p.To) {   // To is a multiple of 64 -> whole float4 valid
          float v0 = acc[g * 4 + 0][cc] + bv;
          float v1 = acc[g * 4 + 1][cc] + bv;
          float v2 = acc[g * 4 + 2][cc] + bv;
          float v3 = acc[g * 4 + 3][cc] + bv;
          if (RELU) {
            v0 = fmaxf(v0, 0.f); v1 = fmaxf(v1, 0.f);
            v2 = fmaxf(v2, 0.f); v3 = fmaxf(v3, 0.f);
          }
          if (OUT_NTC) {
            const int base = (b * p.To + t0) * p.Co + co;
            p.out[base] = v0;
            p.out[base + p.Co] = v1;
            p.out[base + 2 * p.Co] = v2;
            p.out[base + 3 * p.Co] = v3;
          } else {
            float4 v4; v4.x = v0; v4.y = v1; v4.z = v2; v4.w = v3;
            *(float4*)&p.out[(b * p.Co + co) * p.To + t0] = v4;
          }
        }
      }
    }
  }
}

// |e_k|^2 in fp64, one wave per code.
__global__ __launch_bounds__(256) void nrm_kernel(const float* __restrict__ emb,
                                                  float* __restrict__ nrm) {
  const int k = blockIdx.x * 4 + (threadIdx.x >> 6);
  const int lane = threadIdx.x & 63;
  const float4 e4 = *(const float4*)&emb[k * 256 + lane * 4];
  double s = (double)e4.x * e4.x + (double)e4.y * e4.y +
             (double)e4.z * e4.z + (double)e4.w * e4.w;
  for (int off = 32; off; off >>= 1) s += __shfl_down(s, off);
  if (lane == 0) nrm[k] = (float)s;
}

// VQ argmin. Block = 128 rows x half codebook (4096). 256 thr = 16tx x 16ty.
// Thread tile 8 rows x 8 codes; z/e staged per 32-d slice, stride 36 (pad).
__global__ __launch_bounds__(256) void vq_kernel(const float* __restrict__ zf,
                                                 const float* __restrict__ emb,
                                                 const float* __restrict__ nrm,
                                                 float* __restrict__ pbest,
                                                 int* __restrict__ pidx) {
  __shared__ float zs[128 * 36];
  __shared__ float es[128 * 36];
  const int tid = threadIdx.x;
  const int tx = tid & 15, ty = tid >> 4;
  const int rb = blockIdx.x >> 1, half = blockIdx.x & 1;
  const int nbase = rb * 128;
  const int cb0 = half * 4096;
  float best[8]; int bk[8];
#pragma unroll
  for (int i = 0; i < 8; ++i) { best[i] = 3.4e38f; bk[i] = 0; }
  for (int ch = 0; ch < 32; ++ch) {
    const int code0 = cb0 + ch * 128;
    float acc[8][8];
#pragma unroll
    for (int i = 0; i < 8; ++i) {
#pragma unroll
      for (int j = 0; j < 8; ++j) acc[i][j] = 0.f;
    }
    for (int e8 = 0; e8 < 8; ++e8) {
      __syncthreads();
#pragma unroll
      for (int i = 0; i < 16; ++i) {
        const int e = i * 256 + tid;
        const int dd = e & 31, r = e >> 5;
        zs[r * 36 + dd] = zf[(nbase + r) * 256 + e8 * 32 + dd];
      }
#pragma unroll
      for (int i = 0; i < 16; ++i) {
        const int e = i * 256 + tid;
        const int dd = e & 31, c = e >> 5;
        es[c * 36 + dd] = emb[(code0 + c) * 256 + e8 * 32 + dd];
      }
      __syncthreads();
#pragma unroll
      for (int ds = 0; ds < 8; ++ds) {
        float4 z4[8], e4[8];
#pragma unroll
        for (int rr = 0; rr < 8; ++rr)
          z4[rr] = *(const float4*)&zs[(rr * 16 + ty) * 36 + ds * 4];
#pragma unroll
        for (int cc = 0; cc < 8; ++cc)
          e4[cc] = *(const float4*)&es[(cc * 16 + tx) * 36 + ds * 4];
#pragma unroll
        for (int rr = 0; rr < 8; ++rr) {
#pragma unroll
          for (int cc = 0; cc < 8; ++cc) {
            float a = acc[rr][cc];
            a = fmaf(z4[rr].x, e4[cc].x, a);
            a = fmaf(z4[rr].y, e4[cc].y, a);
            a = fmaf(z4[rr].z, e4[cc].z, a);
            a = fmaf(z4[rr].w, e4[cc].w, a);
            acc[rr][cc] = a;
          }
        }
      }
    }
    // dist = |e|^2 - 2 z.e ; argmin with first-k tie-break
#pragma unroll
    for (int cc = 0; cc < 8; ++cc) {
      const int k = code0 + cc * 16 + tx;
      const float nv = nrm[k];
#pragma unroll
      for (int rr = 0; rr < 8; ++rr) {
        const float d = nv - 2.f * acc[rr][cc];
        if (d < best[rr] || (d == best[rr] && k < bk[rr])) { best[rr] = d; bk[rr] = k; }
      }
    }
  }
  // reduce across the 16 tx lanes (within wave: tx = lane & 15)
#pragma unroll
  for (int rr = 0; rr < 8; ++rr) {
    float bv = best[rr]; int kv = bk[rr];
    for (int off = 1; off < 16; off <<= 1) {
      const float ob = __shfl_xor(bv, off);
      const int ok = __shfl_xor(kv, off);
      if (ob < bv || (ob == bv && ok < kv)) { bv = ob; kv = ok; }
    }
    if (tx == 0) {
      const int n = nbase + rr * 16 + ty;
      pbest[half * 16384 + n] = bv;
      pidx[half * 16384 + n] = kv;
    }
  }
}

__global__ void merge_kernel(const float* __restrict__ pbest, const int* __restrict__ pidx,
                             int* __restrict__ vidx, float* __restrict__ out_idx,
                             float* __restrict__ lacc) {
  const int n = blockIdx.x * 256 + threadIdx.x;
  const float b0 = pbest[n]; const int k0 = pidx[n];
  const float b1 = pbest[16384 + n]; const int k1 = pidx[16384 + n];
  const int k = (b1 < b0 || (b1 == b0 && k1 < k0)) ? k1 : k0;
  vidx[n] = k;
  out_idx[n] = (float)k;
  if (n == 0) *lacc = 0.f;   // zero loss accumulator (ws is poisoned)
}

__global__ __launch_bounds__(256) void loss_kernel(const float* __restrict__ zf,
                                                   const float* __restrict__ emb,
                                                   const int* __restrict__ vidx,
                                                   float* __restrict__ lacc) {
  const int e0 = (blockIdx.x * 256 + threadIdx.x) * 4;   // 4096 blocks covers 4.19M
  const int n = e0 >> 8, c = e0 & 255;
  const float4 z4 = *(const float4*)&zf[e0];
  const float4 q4 = *(const float4*)&emb[vidx[n] * 256 + c];
  const float dx = z4.x - q4.x, dy = z4.y - q4.y, dz = z4.z - q4.z, dw = z4.w - q4.w;
  float s = dx * dx + dy * dy + dz * dz + dw * dw;
  for (int off = 32; off; off >>= 1) s += __shfl_down(s, off);
  __shared__ float red[4];
  if ((threadIdx.x & 63) == 0) red[threadIdx.x >> 6] = s;
  __syncthreads();
  if (threadIdx.x == 0) atomicAdd(lacc, red[0] + red[1] + red[2] + red[3]);
}

__global__ void fin_kernel(const float* __restrict__ lacc, float* __restrict__ out, int loff) {
  if (threadIdx.x == 0) {
    const float l = *lacc * (1.f / 4194304.f);
    out[loff] = l;       // codebook_loss
    out[loff + 1] = l;   // commitment_loss (numerically identical in fwd)
  }
}

extern "C" void kernel_launch(void* const* d_in, const int* in_sizes, int n_in,
                              void* d_out, int out_size, void* d_ws, size_t ws_size,
                              hipStream_t stream) {
  const float* x   = (const float*)d_in[0];
  const float* ew0 = (const float*)d_in[1];  const float* eb0 = (const float*)d_in[2];
  const float* ew1 = (const float*)d_in[3];  const float* eb1 = (const float*)d_in[4];
  const float* ew2 = (const float*)d_in[5];  const float* eb2 = (const float*)d_in[6];
  const float* pw  = (const float*)d_in[7];  const float* pb  = (const float*)d_in[8];
  const float* emb = (const float*)d_in[9];
  const float* dw0 = (const float*)d_in[10]; const float* db0 = (const float*)d_in[11];
  const float* dw1 = (const float*)d_in[12]; const float* db1 = (const float*)d_in[13];
  const float* dw2 = (const float*)d_in[14]; const float* db2 = (const float*)d_in[15];
  const float* dw3 = (const float*)d_in[16]; const float* db3 = (const float*)d_in[17];
  float* ws  = (float*)d_ws;
  float* out = (float*)d_out;

  // workspace layout (floats), ping-pong reuse; peak ~67.5 MB
  float* h1 = ws + 0;          // (256,64,256)
  float* h2 = ws + 4194304;    // (256,128,128)
  float* h3 = ws + 8388608;    // (256,256,64)
  float* zf = ws + 12582912;   // (16384,256) flat (n,c)
  float* d1 = ws + 0;          // (256,256,128) over h1+h2 (dead)
  float* d2 = ws + 8388608;    // (256,128,256) over h3+zf (dead after loss)
  float* d3 = ws + 0;          // (256,64,512) over d1 (dead)
  float* nrm   = ws + 16777216;
  float* pbest = ws + 16777216 + 8192;
  int*   pidx  = (int*)(ws + 16777216 + 8192 + 32768);
  int*   vidx  = (int*)(ws + 16777216 + 8192 + 32768 + 32768);
  float* lacc  = ws + 16777216 + 8192 + 32768 + 32768 + 16384;

  const int idx_off = out_size - 16384;   // indices (B,64) as float
  const int loss_off = out_size - 16386;  // two scalar losses

  CP p;
  p.vidx = nullptr; p.emb = nullptr;

  // ---- encoder ----
  p.in = x;  p.w = ew0; p.bias = eb0; p.out = h1;
  p.Ci = 32;  p.Ti = 512; p.Co = 64;  p.To = 256; p.KW = 3; p.K2 = 96;  p.stride = 2; p.pad = 1;
  conv_kernel<false, true, false, true, false><<<dim3(2, 1, 256), 128, 0, stream>>>(p);

  p.in = h1; p.w = ew1; p.bias = eb1; p.out = h2;
  p.Ci = 64;  p.Ti = 256; p.Co = 128; p.To = 128; p.K2 = 192;
  conv_kernel<false, false, false, true, false><<<dim3(1, 2, 256), 128, 0, stream>>>(p);

  p.in = h2; p.w = ew2; p.bias = eb2; p.out = h3;
  p.Ci = 128; p.Ti = 128; p.Co = 256; p.To = 64;  p.K2 = 384;
  conv_kernel<false, false, false, true, false><<<dim3(1, 4, 256), 128, 0, stream>>>(p);

  // proj (1x1), writes flat (n,c) layout via NTC epilogue
  p.in = h3; p.w = pw; p.bias = pb; p.out = zf;
  p.Ci = 256; p.Ti = 64; p.Co = 256; p.To = 64; p.KW = 1; p.K2 = 256; p.stride = 1; p.pad = 0;
  conv_kernel<false, false, true, false, false><<<dim3(1, 4, 256), 128, 0, stream>>>(p);

  // ---- VQ ----
  nrm_kernel<<<2048, 256, 0, stream>>>(emb, nrm);
  vq_kernel<<<256, 256, 0, stream>>>(zf, emb, nrm, pbest, pidx);
  merge_kernel<<<64, 256, 0, stream>>>(pbest, pidx, vidx, out + idx_off, lacc);
  loss_kernel<<<4096, 256, 0, stream>>>(zf, emb, vidx, lacc);
  fin_kernel<<<1, 64, 0, stream>>>(lacc, out, loss_off);

  // ---- decoder (dec0 gathers z_q = emb[idx] directly) ----
  p.in = nullptr; p.w = dw0; p.bias = db0; p.out = d1; p.vidx = vidx; p.emb = emb;
  p.Ci = 256; p.Ti = 64;  p.Co = 256; p.To = 128; p.KW = 3; p.K2 = 768;
  conv_kernel<true, false, false, true, true><<<dim3(1, 4, 256), 128, 0, stream>>>(p);

  p.in = d1; p.w = dw1; p.bias = db1; p.out = d2; p.vidx = nullptr; p.emb = nullptr;
  p.Ci = 256; p.Ti = 128; p.Co = 128; p.To = 256; p.K2 = 768;
  conv_kernel<true, false, false, true, false><<<dim3(2, 2, 256), 128, 0, stream>>>(p);

  p.in = d2; p.w = dw2; p.bias = db2; p.out = d3;
  p.Ci = 128; p.Ti = 256; p.Co = 64;  p.To = 512; p.K2 = 384;
  conv_kernel<true, false, false, true, false><<<dim3(4, 1, 256), 128, 0, stream>>>(p);

  // final deconv, no relu, writes d_out in (B, T, A) layout directly
  p.in = d3; p.w = dw3; p.bias = db3; p.out = out;
  p.Ci = 64;  p.Ti = 512; p.Co = 32;  p.To = 1024; p.K2 = 192;
  conv_kernel<true, false, true, false, false><<<dim3(8, 1, 256), 128, 0, stream>>>(p);
}

// Round 2
// 2344.773 us; speedup vs baseline: 1.7510x; 1.7510x over previous
//
#include <hip/hip_runtime.h>

// ---------------------------------------------------------------------------
// VQ-VAE forward (fp32). R2: occupancy + deconv-parity round.
//  - conv/deconv/proj: OUT[co,bt] = sum_{K'=(ci,k)} W[co,K'] * IM[K',bt]
//    * (b,t) flattened into one tile axis (no idle lanes at To=64)
//    * deconvs split by output parity: even = 1 tap (1x1), odd = 2 taps
//      -> halves decoder FLOPs vs lhs-dilated form (zero taps dropped;
//         fp sum order unchanged since dropped terms were +0.f)
//    * 256 thr, 256bt x 64co block tile, K-chunk 32, LDS 40KB -> 4 blocks/CU
//  - VQ: 8-way codebook split -> 1024 blocks (~4 blocks/CU vs 1 before);
//    inner loop restructured (single e4) to fit 128 VGPR @ launch_bounds(256,4)
//    fp accumulation order identical to R1 (argmin-safe).
// ---------------------------------------------------------------------------

struct CP {
  const float* in; const float* w; const float* bias; float* out;
  const int* vidx; const float* emb;
  int Ci, Ti, Co, To, KWO, K2, stride, pad, lg2U, Umask;
};

// PAR: -1 normal conv (stride/pad), 0 deconv-even (tap k=1), 1 deconv-odd
// (taps k=0,2). NKW: taps per ci in the REDUCED K' enumeration (3/1/2).
template<int PAR, int NKW, bool IN_NTC, bool OUT_NTC, bool RELU, bool IN_EMB>
__global__ __launch_bounds__(256, 4) void conv_kernel(CP p) {
  __shared__ float IMs[32 * 256];
  __shared__ float WTs[32 * 64];
  const int tid = threadIdx.x;
  const int tx = tid & 31, ty = tid >> 5;
  const int gubase = blockIdx.x * 256;
  const int cobase = blockIdx.y * 64;
  float acc[8][8];
#pragma unroll
  for (int i = 0; i < 8; ++i)
#pragma unroll
    for (int j = 0; j < 8; ++j) acc[i][j] = 0.f;

  const int nch = p.K2 >> 5;
  for (int ch = 0; ch < nch; ++ch) {
    const int kbase = ch << 5;
    __syncthreads();
    // ---- stage W: WTs[kk][co], writes conflict-free (co-inner), reads bcast
#pragma unroll
    for (int i = 0; i < 8; ++i) {
      const int e = i * 256 + tid;
      const int co = e & 63, kk = e >> 6;
      const int kg = kbase + kk;
      int ci, ko;
      if (PAR == 0)      { ci = kg;      ko = 1; }
      else if (PAR == 1) { ci = kg >> 1; ko = (kg & 1) * 2; }
      else if (NKW == 1) { ci = kg;      ko = 0; }
      else               { ci = kg / 3;  ko = kg - ci * 3; }
      const int cog = cobase + co;
      float v = 0.f;
      if (cog < p.Co) v = p.w[(cog * p.Ci + ci) * p.KWO + ko];
      WTs[kk * 64 + co] = v;
    }
    // ---- stage IM[kk][bt]: kg uniform per i -> scalar tap math
#pragma unroll 8
    for (int i = 0; i < 32; ++i) {
      const int kg = kbase + i;
      int ci, kp;
      if (PAR == 0)      { ci = kg;      kp = 0; }
      else if (PAR == 1) { ci = kg >> 1; kp = kg & 1; }
      else if (NKW == 1) { ci = kg;      kp = 0; }
      else               { ci = kg / 3;  kp = kg - ci * 3; }
      const int gu = gubase + tid;
      const int b = gu >> p.lg2U;
      const int u = gu & p.Umask;
      int tin; bool ok;
      if (PAR >= 0) { tin = u + kp; ok = (tin < p.Ti); }
      else { tin = u * p.stride + kp - p.pad; ok = (tin >= 0) && (tin < p.Ti); }
      float v = 0.f;
      if (ok) {
        if (IN_EMB)      v = p.emb[p.vidx[b * p.Ti + tin] * 256 + ci];
        else if (IN_NTC) v = p.in[(b * p.Ti + tin) * p.Ci + ci];
        else             v = p.in[(b * p.Ci + ci) * p.Ti + tin];
      }
      IMs[i * 256 + tid] = v;
    }
    __syncthreads();
    // ---- FMA: per kk, x-tile b128 x2, w-tile b128 x2 (broadcast)
#pragma unroll 4
    for (int kk = 0; kk < 32; ++kk) {
      const float4 x0 = *(const float4*)&IMs[kk * 256 + tx * 4];
      const float4 x1 = *(const float4*)&IMs[kk * 256 + tx * 4 + 128];
      const float4 wa = *(const float4*)&WTs[kk * 64 + ty * 8];
      const float4 wb = *(const float4*)&WTs[kk * 64 + ty * 8 + 4];
      const float wv[8] = {wa.x, wa.y, wa.z, wa.w, wb.x, wb.y, wb.z, wb.w};
#pragma unroll
      for (int cc = 0; cc < 8; ++cc) {
        acc[0][cc] = fmaf(x0.x, wv[cc], acc[0][cc]);
        acc[1][cc] = fmaf(x0.y, wv[cc], acc[1][cc]);
        acc[2][cc] = fmaf(x0.z, wv[cc], acc[2][cc]);
        acc[3][cc] = fmaf(x0.w, wv[cc], acc[3][cc]);
        acc[4][cc] = fmaf(x1.x, wv[cc], acc[4][cc]);
        acc[5][cc] = fmaf(x1.y, wv[cc], acc[5][cc]);
        acc[6][cc] = fmaf(x1.z, wv[cc], acc[6][cc]);
        acc[7][cc] = fmaf(x1.w, wv[cc], acc[7][cc]);
      }
    }
  }
  // ---- epilogue
#pragma unroll
  for (int cc = 0; cc < 8; ++cc) {
    const int cog = cobase + ty * 8 + cc;
    if (cog < p.Co) {
      const float bv = p.bias[cog];
#pragma unroll
      for (int g = 0; g < 2; ++g) {
        const int gu0 = gubase + tx * 4 + g * 128;
        const int b = gu0 >> p.lg2U;
        const int ul = gu0 & p.Umask;
        float v[4];
#pragma unroll
        for (int j = 0; j < 4; ++j) {
          v[j] = acc[g * 4 + j][cc] + bv;
          if (RELU) v[j] = fmaxf(v[j], 0.f);
        }
        if (PAR < 0) {
          if (OUT_NTC) {
            const int base = (b * p.To + ul) * p.Co + cog;
            p.out[base] = v[0]; p.out[base + p.Co] = v[1];
            p.out[base + 2 * p.Co] = v[2]; p.out[base + 3 * p.Co] = v[3];
          } else {
            float4 v4; v4.x = v[0]; v4.y = v[1]; v4.z = v[2]; v4.w = v[3];
            *(float4*)&p.out[(b * p.Co + cog) * p.To + ul] = v4;
          }
        } else {
#pragma unroll
          for (int j = 0; j < 4; ++j) {
            const int t = 2 * (ul + j) + PAR;
            if (OUT_NTC) p.out[(b * p.To + t) * p.Co + cog] = v[j];
            else         p.out[(b * p.Co + cog) * p.To + t] = v[j];
          }
        }
      }
    }
  }
}

// |e_k|^2 in fp64, one wave per code.
__global__ __launch_bounds__(256) void nrm_kernel(const float* __restrict__ emb,
                                                  float* __restrict__ nrm) {
  const int k = blockIdx.x * 4 + (threadIdx.x >> 6);
  const int lane = threadIdx.x & 63;
  const float4 e4 = *(const float4*)&emb[k * 256 + lane * 4];
  double s = (double)e4.x * e4.x + (double)e4.y * e4.y +
             (double)e4.z * e4.z + (double)e4.w * e4.w;
  for (int off = 32; off; off >>= 1) s += __shfl_down(s, off);
  if (lane == 0) nrm[k] = (float)s;
}

// VQ argmin. 1024 blocks = 128 row-blocks x 8 codebook segments (1024 codes).
// 256 thr = 16tx(codes) x 16ty(rows); thread tile 8r x 8c; 32-d LDS slices
// stride 36 (2-way conflicts only = free). FP order identical to R1.
__global__ __launch_bounds__(256, 4) void vq_kernel(const float* __restrict__ zf,
                                                    const float* __restrict__ emb,
                                                    const float* __restrict__ nrm,
                                                    float* __restrict__ pbest,
                                                    int* __restrict__ pidx) {
  __shared__ float zs[128 * 36];
  __shared__ float es[128 * 36];
  const int tid = threadIdx.x;
  const int tx = tid & 15, ty = tid >> 4;
  const int rb = blockIdx.x >> 3, seg = blockIdx.x & 7;
  const int nbase = rb * 128;
  const int cb0 = seg * 1024;
  float best[8]; int bk[8];
#pragma unroll
  for (int i = 0; i < 8; ++i) { best[i] = 3.4e38f; bk[i] = 0; }
  for (int ch = 0; ch < 8; ++ch) {
    const int code0 = cb0 + ch * 128;
    float acc[8][8];
#pragma unroll
    for (int i = 0; i < 8; ++i)
#pragma unroll
      for (int j = 0; j < 8; ++j) acc[i][j] = 0.f;
    for (int e8 = 0; e8 < 8; ++e8) {
      __syncthreads();
#pragma unroll
      for (int i = 0; i < 4; ++i) {
        const int e = i * 256 + tid;
        const int r = e >> 3, d4 = e & 7;
        const float4 v = *(const float4*)&zf[(nbase + r) * 256 + e8 * 32 + d4 * 4];
        *(float4*)&zs[r * 36 + d4 * 4] = v;
      }
#pragma unroll
      for (int i = 0; i < 4; ++i) {
        const int e = i * 256 + tid;
        const int c = e >> 3, d4 = e & 7;
        const float4 v = *(const float4*)&emb[(code0 + c) * 256 + e8 * 32 + d4 * 4];
        *(float4*)&es[c * 36 + d4 * 4] = v;
      }
      __syncthreads();
#pragma unroll
      for (int ds = 0; ds < 8; ++ds) {
        float4 z4[8];
#pragma unroll
        for (int rr = 0; rr < 8; ++rr)
          z4[rr] = *(const float4*)&zs[(rr * 16 + ty) * 36 + ds * 4];
#pragma unroll
        for (int cc = 0; cc < 8; ++cc) {
          const float4 e4 = *(const float4*)&es[(cc * 16 + tx) * 36 + ds * 4];
#pragma unroll
          for (int rr = 0; rr < 8; ++rr) {
            float a = acc[rr][cc];
            a = fmaf(z4[rr].x, e4.x, a);
            a = fmaf(z4[rr].y, e4.y, a);
            a = fmaf(z4[rr].z, e4.z, a);
            a = fmaf(z4[rr].w, e4.w, a);
            acc[rr][cc] = a;
          }
        }
      }
    }
#pragma unroll
    for (int cc = 0; cc < 8; ++cc) {
      const int k = code0 + cc * 16 + tx;
      const float nv = nrm[k];
#pragma unroll
      for (int rr = 0; rr < 8; ++rr) {
        const float d = nv - 2.f * acc[rr][cc];
        if (d < best[rr] || (d == best[rr] && k < bk[rr])) { best[rr] = d; bk[rr] = k; }
      }
    }
  }
#pragma unroll
  for (int rr = 0; rr < 8; ++rr) {
    float bv = best[rr]; int kv = bk[rr];
    for (int off = 1; off < 16; off <<= 1) {
      const float ob = __shfl_xor(bv, off);
      const int ok = __shfl_xor(kv, off);
      if (ob < bv || (ob == bv && ok < kv)) { bv = ob; kv = ok; }
    }
    if (tx == 0) {
      const int n = nbase + rr * 16 + ty;
      pbest[seg * 16384 + n] = bv;
      pidx[seg * 16384 + n] = kv;
    }
  }
}

__global__ void merge_kernel(const float* __restrict__ pbest, const int* __restrict__ pidx,
                             int* __restrict__ vidx, float* __restrict__ out_idx,
                             float* __restrict__ lacc) {
  const int n = blockIdx.x * 256 + threadIdx.x;
  float bv = pbest[n]; int kv = pidx[n];
#pragma unroll
  for (int s = 1; s < 8; ++s) {
    const float ob = pbest[s * 16384 + n];
    const int ok = pidx[s * 16384 + n];
    if (ob < bv || (ob == bv && ok < kv)) { bv = ob; kv = ok; }
  }
  vidx[n] = kv;
  out_idx[n] = (float)kv;
  if (n == 0) *lacc = 0.f;   // ws is poisoned; zero the loss accumulator
}

__global__ __launch_bounds__(256) void loss_kernel(const float* __restrict__ zf,
                                                   const float* __restrict__ emb,
                                                   const int* __restrict__ vidx,
                                                   float* __restrict__ lacc) {
  const int e0 = (blockIdx.x * 256 + threadIdx.x) * 4;
  const int n = e0 >> 8, c = e0 & 255;
  const float4 z4 = *(const float4*)&zf[e0];
  const float4 q4 = *(const float4*)&emb[vidx[n] * 256 + c];
  const float dx = z4.x - q4.x, dy = z4.y - q4.y, dz = z4.z - q4.z, dw = z4.w - q4.w;
  float s = dx * dx + dy * dy + dz * dz + dw * dw;
  for (int off = 32; off; off >>= 1) s += __shfl_down(s, off);
  __shared__ float red[4];
  if ((threadIdx.x & 63) == 0) red[threadIdx.x >> 6] = s;
  __syncthreads();
  if (threadIdx.x == 0) atomicAdd(lacc, red[0] + red[1] + red[2] + red[3]);
}

__global__ void fin_kernel(const float* __restrict__ lacc, float* __restrict__ out, int loff) {
  if (threadIdx.x == 0) {
    const float l = *lacc * (1.f / 4194304.f);
    out[loff] = l;
    out[loff + 1] = l;
  }
}

extern "C" void kernel_launch(void* const* d_in, const int* in_sizes, int n_in,
                              void* d_out, int out_size, void* d_ws, size_t ws_size,
                              hipStream_t stream) {
  const float* x   = (const float*)d_in[0];
  const float* ew0 = (const float*)d_in[1];  const float* eb0 = (const float*)d_in[2];
  const float* ew1 = (const float*)d_in[3];  const float* eb1 = (const float*)d_in[4];
  const float* ew2 = (const float*)d_in[5];  const float* eb2 = (const float*)d_in[6];
  const float* pw  = (const float*)d_in[7];  const float* pb  = (const float*)d_in[8];
  const float* emb = (const float*)d_in[9];
  const float* dw0 = (const float*)d_in[10]; const float* db0 = (const float*)d_in[11];
  const float* dw1 = (const float*)d_in[12]; const float* db1 = (const float*)d_in[13];
  const float* dw2 = (const float*)d_in[14]; const float* db2 = (const float*)d_in[15];
  const float* dw3 = (const float*)d_in[16]; const float* db3 = (const float*)d_in[17];
  float* ws  = (float*)d_ws;
  float* out = (float*)d_out;

  // workspace (floats): conv ping-pong in [0, 16.78M); VQ partials overlay the
  // dead d1 region during the VQ phase; tail holds nrm/vidx/lacc.
  float* h1 = ws + 0;          // (256,64,256)
  float* h2 = ws + 4194304;    // (256,128,128)
  float* h3 = ws + 8388608;    // (256,256,64)
  float* zf = ws + 12582912;   // (16384,256) flat (n,c)
  float* d1 = ws + 0;          // (256,256,128)
  float* d2 = ws + 8388608;    // (256,128,256)
  float* d3 = ws + 0;          // (256,64,512)
  float* pbest = ws + 0;                       // 8*16384, dead before dec0
  int*   pidx  = (int*)(ws + 131072);          // 8*16384
  float* nrm   = ws + 16777216;                // 8192
  int*   vidx  = (int*)(ws + 16785408);        // 16384 (live through dec0)
  float* lacc  = ws + 16801792;                // 1

  const int idx_off  = out_size - 16384;
  const int loss_off = out_size - 16386;

  CP p; p.vidx = nullptr; p.emb = nullptr;

  // ---- encoder ----
  p.in = x;  p.w = ew0; p.bias = eb0; p.out = h1;
  p.Ci = 32;  p.Ti = 512; p.Co = 64;  p.To = 256; p.KWO = 3; p.K2 = 96;
  p.stride = 2; p.pad = 1; p.lg2U = 8; p.Umask = 255;
  conv_kernel<-1, 3, true, false, true, false><<<dim3(256, 1), 256, 0, stream>>>(p);

  p.in = h1; p.w = ew1; p.bias = eb1; p.out = h2;
  p.Ci = 64;  p.Ti = 256; p.Co = 128; p.To = 128; p.K2 = 192; p.lg2U = 7; p.Umask = 127;
  conv_kernel<-1, 3, false, false, true, false><<<dim3(128, 2), 256, 0, stream>>>(p);

  p.in = h2; p.w = ew2; p.bias = eb2; p.out = h3;
  p.Ci = 128; p.Ti = 128; p.Co = 256; p.To = 64; p.K2 = 384; p.lg2U = 6; p.Umask = 63;
  conv_kernel<-1, 3, false, false, true, false><<<dim3(64, 4), 256, 0, stream>>>(p);

  p.in = h3; p.w = pw; p.bias = pb; p.out = zf;
  p.Ci = 256; p.Ti = 64; p.Co = 256; p.To = 64; p.KWO = 1; p.K2 = 256;
  p.stride = 1; p.pad = 0; p.lg2U = 6; p.Umask = 63;
  conv_kernel<-1, 1, false, true, false, false><<<dim3(64, 4), 256, 0, stream>>>(p);

  // ---- VQ ----
  nrm_kernel<<<2048, 256, 0, stream>>>(emb, nrm);
  vq_kernel<<<1024, 256, 0, stream>>>(zf, emb, nrm, pbest, pidx);
  merge_kernel<<<64, 256, 0, stream>>>(pbest, pidx, vidx, out + idx_off, lacc);
  loss_kernel<<<4096, 256, 0, stream>>>(zf, emb, vidx, lacc);
  fin_kernel<<<1, 64, 0, stream>>>(lacc, out, loss_off);

  // ---- decoder: each deconv = even (1 tap) + odd (2 taps) sub-convs ----
  p.w = dw0; p.bias = db0; p.out = d1; p.in = nullptr; p.vidx = vidx; p.emb = emb;
  p.Ci = 256; p.Ti = 64; p.Co = 256; p.To = 128; p.KWO = 3; p.lg2U = 6; p.Umask = 63;
  p.K2 = 256; conv_kernel<0, 1, false, false, true, true><<<dim3(64, 4), 256, 0, stream>>>(p);
  p.K2 = 512; conv_kernel<1, 2, false, false, true, true><<<dim3(64, 4), 256, 0, stream>>>(p);

  p.in = d1; p.w = dw1; p.bias = db1; p.out = d2; p.vidx = nullptr; p.emb = nullptr;
  p.Ci = 256; p.Ti = 128; p.Co = 128; p.To = 256; p.lg2U = 7; p.Umask = 127;
  p.K2 = 256; conv_kernel<0, 1, false, false, true, false><<<dim3(128, 2), 256, 0, stream>>>(p);
  p.K2 = 512; conv_kernel<1, 2, false, false, true, false><<<dim3(128, 2), 256, 0, stream>>>(p);

  p.in = d2; p.w = dw2; p.bias = db2; p.out = d3;
  p.Ci = 128; p.Ti = 256; p.Co = 64; p.To = 512; p.lg2U = 8; p.Umask = 255;
  p.K2 = 128; conv_kernel<0, 1, false, false, true, false><<<dim3(256, 1), 256, 0, stream>>>(p);
  p.K2 = 256; conv_kernel<1, 2, false, false, true, false><<<dim3(256, 1), 256, 0, stream>>>(p);

  p.in = d3; p.w = dw3; p.bias = db3; p.out = out;
  p.Ci = 64; p.Ti = 512; p.Co = 32; p.To = 1024; p.lg2U = 9; p.Umask = 511;
  p.K2 = 64;  conv_kernel<0, 1, false, true, false, false><<<dim3(512, 1), 256, 0, stream>>>(p);
  p.K2 = 128; conv_kernel<1, 2, false, true, false, false><<<dim3(512, 1), 256, 0, stream>>>(p);
}

// Round 3
// 1917.749 us; speedup vs baseline: 2.1409x; 1.2227x over previous
//
#include <hip/hip_runtime.h>

// ---------------------------------------------------------------------------
// VQ-VAE forward. R3: VQ distance matmul moved to f16 MFMA (3-pass split).
//   z = z1 + z2, e = e1 + e2 (f16 hi + f16 residual, rel err 2^-11 each)
//   z.e = z1e1 + z2e1 + z1e2  (dropped z2e2 ~ 2e-9 << fp32 noise)
//   -> distances at fp32 accuracy, computed at MFMA rate.
// Fused per-row argmin in MFMA C-layout (col=lane&15, row=quad*4+reg),
// first-k tie-break preserved. Convs unchanged from R2 (next round).
// ---------------------------------------------------------------------------

typedef _Float16 half8 __attribute__((ext_vector_type(8)));
typedef _Float16 half4v __attribute__((ext_vector_type(4)));
typedef float f32x4 __attribute__((ext_vector_type(4)));

struct CP {
  const float* in; const float* w; const float* bias; float* out;
  const int* vidx; const float* emb;
  int Ci, Ti, Co, To, KWO, K2, stride, pad, lg2U, Umask;
};

// PAR: -1 normal conv (stride/pad), 0 deconv-even (tap k=1), 1 deconv-odd
// (taps k=0,2). NKW: taps per ci in the REDUCED K' enumeration (3/1/2).
template<int PAR, int NKW, bool IN_NTC, bool OUT_NTC, bool RELU, bool IN_EMB>
__global__ __launch_bounds__(256, 4) void conv_kernel(CP p) {
  __shared__ float IMs[32 * 256];
  __shared__ float WTs[32 * 64];
  const int tid = threadIdx.x;
  const int tx = tid & 31, ty = tid >> 5;
  const int gubase = blockIdx.x * 256;
  const int cobase = blockIdx.y * 64;
  float acc[8][8];
#pragma unroll
  for (int i = 0; i < 8; ++i)
#pragma unroll
    for (int j = 0; j < 8; ++j) acc[i][j] = 0.f;

  const int nch = p.K2 >> 5;
  for (int ch = 0; ch < nch; ++ch) {
    const int kbase = ch << 5;
    __syncthreads();
#pragma unroll
    for (int i = 0; i < 8; ++i) {
      const int e = i * 256 + tid;
      const int co = e & 63, kk = e >> 6;
      const int kg = kbase + kk;
      int ci, ko;
      if (PAR == 0)      { ci = kg;      ko = 1; }
      else if (PAR == 1) { ci = kg >> 1; ko = (kg & 1) * 2; }
      else if (NKW == 1) { ci = kg;      ko = 0; }
      else               { ci = kg / 3;  ko = kg - ci * 3; }
      const int cog = cobase + co;
      float v = 0.f;
      if (cog < p.Co) v = p.w[(cog * p.Ci + ci) * p.KWO + ko];
      WTs[kk * 64 + co] = v;
    }
#pragma unroll 8
    for (int i = 0; i < 32; ++i) {
      const int kg = kbase + i;
      int ci, kp;
      if (PAR == 0)      { ci = kg;      kp = 0; }
      else if (PAR == 1) { ci = kg >> 1; kp = kg & 1; }
      else if (NKW == 1) { ci = kg;      kp = 0; }
      else               { ci = kg / 3;  kp = kg - ci * 3; }
      const int gu = gubase + tid;
      const int b = gu >> p.lg2U;
      const int u = gu & p.Umask;
      int tin; bool ok;
      if (PAR >= 0) { tin = u + kp; ok = (tin < p.Ti); }
      else { tin = u * p.stride + kp - p.pad; ok = (tin >= 0) && (tin < p.Ti); }
      float v = 0.f;
      if (ok) {
        if (IN_EMB)      v = p.emb[p.vidx[b * p.Ti + tin] * 256 + ci];
        else if (IN_NTC) v = p.in[(b * p.Ti + tin) * p.Ci + ci];
        else             v = p.in[(b * p.Ci + ci) * p.Ti + tin];
      }
      IMs[i * 256 + tid] = v;
    }
    __syncthreads();
#pragma unroll 4
    for (int kk = 0; kk < 32; ++kk) {
      const float4 x0 = *(const float4*)&IMs[kk * 256 + tx * 4];
      const float4 x1 = *(const float4*)&IMs[kk * 256 + tx * 4 + 128];
      const float4 wa = *(const float4*)&WTs[kk * 64 + ty * 8];
      const float4 wb = *(const float4*)&WTs[kk * 64 + ty * 8 + 4];
      const float wv[8] = {wa.x, wa.y, wa.z, wa.w, wb.x, wb.y, wb.z, wb.w};
#pragma unroll
      for (int cc = 0; cc < 8; ++cc) {
        acc[0][cc] = fmaf(x0.x, wv[cc], acc[0][cc]);
        acc[1][cc] = fmaf(x0.y, wv[cc], acc[1][cc]);
        acc[2][cc] = fmaf(x0.z, wv[cc], acc[2][cc]);
        acc[3][cc] = fmaf(x0.w, wv[cc], acc[3][cc]);
        acc[4][cc] = fmaf(x1.x, wv[cc], acc[4][cc]);
        acc[5][cc] = fmaf(x1.y, wv[cc], acc[5][cc]);
        acc[6][cc] = fmaf(x1.z, wv[cc], acc[6][cc]);
        acc[7][cc] = fmaf(x1.w, wv[cc], acc[7][cc]);
      }
    }
  }
#pragma unroll
  for (int cc = 0; cc < 8; ++cc) {
    const int cog = cobase + ty * 8 + cc;
    if (cog < p.Co) {
      const float bv = p.bias[cog];
#pragma unroll
      for (int g = 0; g < 2; ++g) {
        const int gu0 = gubase + tx * 4 + g * 128;
        const int b = gu0 >> p.lg2U;
        const int ul = gu0 & p.Umask;
        float v[4];
#pragma unroll
        for (int j = 0; j < 4; ++j) {
          v[j] = acc[g * 4 + j][cc] + bv;
          if (RELU) v[j] = fmaxf(v[j], 0.f);
        }
        if (PAR < 0) {
          if (OUT_NTC) {
            const int base = (b * p.To + ul) * p.Co + cog;
            p.out[base] = v[0]; p.out[base + p.Co] = v[1];
            p.out[base + 2 * p.Co] = v[2]; p.out[base + 3 * p.Co] = v[3];
          } else {
            float4 v4; v4.x = v[0]; v4.y = v[1]; v4.z = v[2]; v4.w = v[3];
            *(float4*)&p.out[(b * p.Co + cog) * p.To + ul] = v4;
          }
        } else {
#pragma unroll
          for (int j = 0; j < 4; ++j) {
            const int t = 2 * (ul + j) + PAR;
            if (OUT_NTC) p.out[(b * p.To + t) * p.Co + cog] = v[j];
            else         p.out[(b * p.Co + cog) * p.To + t] = v[j];
          }
        }
      }
    }
  }
}

// split fp32 -> f16 hi + f16 residual, 4 elems/thread
__global__ __launch_bounds__(256) void split_kernel(const float* __restrict__ src,
                                                    _Float16* __restrict__ hi,
                                                    _Float16* __restrict__ lo) {
  const int i = blockIdx.x * 256 + threadIdx.x;
  const float4 v = ((const float4*)src)[i];
  half4v a, b;
  a.x = (_Float16)v.x; b.x = (_Float16)(v.x - (float)a.x);
  a.y = (_Float16)v.y; b.y = (_Float16)(v.y - (float)a.y);
  a.z = (_Float16)v.z; b.z = (_Float16)(v.z - (float)a.z);
  a.w = (_Float16)v.w; b.w = (_Float16)(v.w - (float)a.w);
  ((half4v*)hi)[i] = a;
  ((half4v*)lo)[i] = b;
}

// |e_k|^2 in fp64, one wave per code.
__global__ __launch_bounds__(256) void nrm_kernel(const float* __restrict__ emb,
                                                  float* __restrict__ nrm) {
  const int k = blockIdx.x * 4 + (threadIdx.x >> 6);
  const int lane = threadIdx.x & 63;
  const float4 e4 = *(const float4*)&emb[k * 256 + lane * 4];
  double s = (double)e4.x * e4.x + (double)e4.y * e4.y +
             (double)e4.z * e4.z + (double)e4.w * e4.w;
  for (int off = 32; off; off >>= 1) s += __shfl_down(s, off);
  if (lane == 0) nrm[k] = (float)s;
}

// VQ argmin via MFMA. Grid 1024 = 128 row-blocks (128 rows) x 8 segs (1024
// codes). Block 4 waves; wave tile = 32 rows x 128 codes of the col-chunk.
// Per col-chunk: K-loop d=256 in 8 chunks of 32; 3 mfma passes per tile.
// LDS: 4 tiles (z1,z2,e1,e2) 128x32 f16, row stride 40 (pad) = 40 KB.
__global__ __launch_bounds__(256, 3) void vq_mfma(const _Float16* __restrict__ z1g,
                                                  const _Float16* __restrict__ z2g,
                                                  const _Float16* __restrict__ e1g,
                                                  const _Float16* __restrict__ e2g,
                                                  const float* __restrict__ nrm,
                                                  float* __restrict__ pbest,
                                                  int* __restrict__ pidx) {
  __shared__ _Float16 lds[4 * 128 * 40];
  const int ZS2 = 5120, ES1 = 10240, ES2 = 15360;
  const int tid = threadIdx.x;
  const int lane = tid & 63;
  const int w = tid >> 6;          // wave id 0..3
  const int m = lane & 15;         // col within 16x16 tile / frag row
  const int q = lane >> 4;         // quad
  const int rb = blockIdx.x >> 3, seg = blockIdx.x & 7;
  const int rbase = rb * 128;
  const int w32 = w * 32;
  const int r2 = tid >> 2, s4 = tid & 3;

  float best[8]; int bk[8];
#pragma unroll
  for (int i = 0; i < 8; ++i) { best[i] = 3.4e38f; bk[i] = 0; }

  for (int cc = 0; cc < 8; ++cc) {           // col-chunks of 128 codes
    const int cbase = seg * 1024 + cc * 128;
    f32x4 acc[2][8];
#pragma unroll
    for (int rt = 0; rt < 2; ++rt)
#pragma unroll
      for (int ct = 0; ct < 8; ++ct) acc[rt][ct] = {0.f, 0.f, 0.f, 0.f};

    for (int kb = 0; kb < 8; ++kb) {         // k-chunks of 32 dims
      const int kof = kb * 32;
      __syncthreads();
#pragma unroll
      for (int i = 0; i < 2; ++i) {
        const int row = i * 64 + r2;
        const int zg = (rbase + row) * 256 + kof + s4 * 8;
        const int eg = (cbase + row) * 256 + kof + s4 * 8;
        const int lo = row * 40 + s4 * 8;
        *(uint4*)&lds[lo]       = *(const uint4*)&z1g[zg];
        *(uint4*)&lds[ZS2 + lo] = *(const uint4*)&z2g[zg];
        *(uint4*)&lds[ES1 + lo] = *(const uint4*)&e1g[eg];
        *(uint4*)&lds[ES2 + lo] = *(const uint4*)&e2g[eg];
      }
      __syncthreads();
      half8 a1[2], a2[2];
#pragma unroll
      for (int rt = 0; rt < 2; ++rt) {
        const int r = w32 + rt * 16 + m;
        a1[rt] = *(const half8*)&lds[r * 40 + q * 8];
        a2[rt] = *(const half8*)&lds[ZS2 + r * 40 + q * 8];
      }
#pragma unroll
      for (int ct = 0; ct < 8; ++ct) {
        const int c = ct * 16 + m;
        const half8 b1 = *(const half8*)&lds[ES1 + c * 40 + q * 8];
        const half8 b2 = *(const half8*)&lds[ES2 + c * 40 + q * 8];
#pragma unroll
        for (int rt = 0; rt < 2; ++rt) {
          acc[rt][ct] = __builtin_amdgcn_mfma_f32_16x16x32_f16(a1[rt], b1, acc[rt][ct], 0, 0, 0);
          acc[rt][ct] = __builtin_amdgcn_mfma_f32_16x16x32_f16(a2[rt], b1, acc[rt][ct], 0, 0, 0);
          acc[rt][ct] = __builtin_amdgcn_mfma_f32_16x16x32_f16(a1[rt], b2, acc[rt][ct], 0, 0, 0);
        }
      }
    }
    // epilogue: dist = |e|^2 - 2 z.e, update per-row best (k ascending)
#pragma unroll
    for (int ct = 0; ct < 8; ++ct) {
      const int k = cbase + ct * 16 + m;
      const float nv = nrm[k];
#pragma unroll
      for (int rt = 0; rt < 2; ++rt)
#pragma unroll
        for (int rg = 0; rg < 4; ++rg) {
          const float d = nv - 2.f * acc[rt][ct][rg];
          const int slot = rt * 4 + rg;
          if (d < best[slot] || (d == best[slot] && k < bk[slot])) {
            best[slot] = d; bk[slot] = k;
          }
        }
    }
  }
  // reduce across the 16 col-lanes (xor masks < 16 stay within quad group)
#pragma unroll
  for (int slot = 0; slot < 8; ++slot) {
    float bv = best[slot]; int kv = bk[slot];
    for (int off = 1; off < 16; off <<= 1) {
      const float ob = __shfl_xor(bv, off);
      const int ok = __shfl_xor(kv, off);
      if (ob < bv || (ob == bv && ok < kv)) { bv = ob; kv = ok; }
    }
    if (m == 0) {
      const int row = rbase + w32 + (slot >> 2) * 16 + q * 4 + (slot & 3);
      pbest[seg * 16384 + row] = bv;
      pidx[seg * 16384 + row] = kv;
    }
  }
}

__global__ void merge_kernel(const float* __restrict__ pbest, const int* __restrict__ pidx,
                             int* __restrict__ vidx, float* __restrict__ out_idx,
                             float* __restrict__ lacc) {
  const int n = blockIdx.x * 256 + threadIdx.x;
  float bv = pbest[n]; int kv = pidx[n];
#pragma unroll
  for (int s = 1; s < 8; ++s) {
    const float ob = pbest[s * 16384 + n];
    const int ok = pidx[s * 16384 + n];
    if (ob < bv || (ob == bv && ok < kv)) { bv = ob; kv = ok; }
  }
  vidx[n] = kv;
  out_idx[n] = (float)kv;
  if (n == 0) *lacc = 0.f;
}

__global__ __launch_bounds__(256) void loss_kernel(const float* __restrict__ zf,
                                                   const float* __restrict__ emb,
                                                   const int* __restrict__ vidx,
                                                   float* __restrict__ lacc) {
  const int e0 = (blockIdx.x * 256 + threadIdx.x) * 4;
  const int n = e0 >> 8, c = e0 & 255;
  const float4 z4 = *(const float4*)&zf[e0];
  const float4 q4 = *(const float4*)&emb[vidx[n] * 256 + c];
  const float dx = z4.x - q4.x, dy = z4.y - q4.y, dz = z4.z - q4.z, dw = z4.w - q4.w;
  float s = dx * dx + dy * dy + dz * dz + dw * dw;
  for (int off = 32; off; off >>= 1) s += __shfl_down(s, off);
  __shared__ float red[4];
  if ((threadIdx.x & 63) == 0) red[threadIdx.x >> 6] = s;
  __syncthreads();
  if (threadIdx.x == 0) atomicAdd(lacc, red[0] + red[1] + red[2] + red[3]);
}

__global__ void fin_kernel(const float* __restrict__ lacc, float* __restrict__ out, int loff) {
  if (threadIdx.x == 0) {
    const float l = *lacc * (1.f / 4194304.f);
    out[loff] = l;
    out[loff + 1] = l;
  }
}

extern "C" void kernel_launch(void* const* d_in, const int* in_sizes, int n_in,
                              void* d_out, int out_size, void* d_ws, size_t ws_size,
                              hipStream_t stream) {
  const float* x   = (const float*)d_in[0];
  const float* ew0 = (const float*)d_in[1];  const float* eb0 = (const float*)d_in[2];
  const float* ew1 = (const float*)d_in[3];  const float* eb1 = (const float*)d_in[4];
  const float* ew2 = (const float*)d_in[5];  const float* eb2 = (const float*)d_in[6];
  const float* pw  = (const float*)d_in[7];  const float* pb  = (const float*)d_in[8];
  const float* emb = (const float*)d_in[9];
  const float* dw0 = (const float*)d_in[10]; const float* db0 = (const float*)d_in[11];
  const float* dw1 = (const float*)d_in[12]; const float* db1 = (const float*)d_in[13];
  const float* dw2 = (const float*)d_in[14]; const float* db2 = (const float*)d_in[15];
  const float* dw3 = (const float*)d_in[16]; const float* db3 = (const float*)d_in[17];
  float* ws  = (float*)d_ws;
  float* out = (float*)d_out;

  // workspace (floats): conv ping-pong in [0, 16.78M); VQ scratch overlays the
  // dead h1/h2 region during the VQ phase; tail holds nrm/vidx/lacc.
  float* h1 = ws + 0;          // (256,64,256)
  float* h2 = ws + 4194304;    // (256,128,128)
  float* h3 = ws + 8388608;    // (256,256,64)
  float* zf = ws + 12582912;   // (16384,256) flat (n,c)
  float* d1 = ws + 0;          // (256,256,128) after VQ
  float* d2 = ws + 8388608;    // (256,128,256)
  float* d3 = ws + 0;          // (256,64,512)
  float* pbest = ws + 0;                       // 8*16384 (dead before dec0)
  int*   pidx  = (int*)(ws + 131072);          // 8*16384
  _Float16* z1g = (_Float16*)(ws + 1048576);   // 16384x256 f16
  _Float16* z2g = (_Float16*)(ws + 3145728);
  _Float16* e1g = (_Float16*)(ws + 5242880);   // 8192x256 f16
  _Float16* e2g = (_Float16*)(ws + 6291456);
  float* nrm   = ws + 16777216;
  int*   vidx  = (int*)(ws + 16785408);
  float* lacc  = ws + 16801792;

  const int idx_off  = out_size - 16384;
  const int loss_off = out_size - 16386;

  CP p; p.vidx = nullptr; p.emb = nullptr;

  // ---- encoder ----
  p.in = x;  p.w = ew0; p.bias = eb0; p.out = h1;
  p.Ci = 32;  p.Ti = 512; p.Co = 64;  p.To = 256; p.KWO = 3; p.K2 = 96;
  p.stride = 2; p.pad = 1; p.lg2U = 8; p.Umask = 255;
  conv_kernel<-1, 3, true, false, true, false><<<dim3(256, 1), 256, 0, stream>>>(p);

  p.in = h1; p.w = ew1; p.bias = eb1; p.out = h2;
  p.Ci = 64;  p.Ti = 256; p.Co = 128; p.To = 128; p.K2 = 192; p.lg2U = 7; p.Umask = 127;
  conv_kernel<-1, 3, false, false, true, false><<<dim3(128, 2), 256, 0, stream>>>(p);

  p.in = h2; p.w = ew2; p.bias = eb2; p.out = h3;
  p.Ci = 128; p.Ti = 128; p.Co = 256; p.To = 64; p.K2 = 384; p.lg2U = 6; p.Umask = 63;
  conv_kernel<-1, 3, false, false, true, false><<<dim3(64, 4), 256, 0, stream>>>(p);

  p.in = h3; p.w = pw; p.bias = pb; p.out = zf;
  p.Ci = 256; p.Ti = 64; p.Co = 256; p.To = 64; p.KWO = 1; p.K2 = 256;
  p.stride = 1; p.pad = 0; p.lg2U = 6; p.Umask = 63;
  conv_kernel<-1, 1, false, true, false, false><<<dim3(64, 4), 256, 0, stream>>>(p);

  // ---- VQ: split to f16 hi/lo, norms, MFMA argmin, merge, losses ----
  split_kernel<<<4096, 256, 0, stream>>>(zf, z1g, z2g);
  split_kernel<<<2048, 256, 0, stream>>>(emb, e1g, e2g);
  nrm_kernel<<<2048, 256, 0, stream>>>(emb, nrm);
  vq_mfma<<<1024, 256, 0, stream>>>(z1g, z2g, e1g, e2g, nrm, pbest, pidx);
  merge_kernel<<<64, 256, 0, stream>>>(pbest, pidx, vidx, out + idx_off, lacc);
  loss_kernel<<<4096, 256, 0, stream>>>(zf, emb, vidx, lacc);
  fin_kernel<<<1, 64, 0, stream>>>(lacc, out, loss_off);

  // ---- decoder: each deconv = even (1 tap) + odd (2 taps) sub-convs ----
  p.w = dw0; p.bias = db0; p.out = d1; p.in = nullptr; p.vidx = vidx; p.emb = emb;
  p.Ci = 256; p.Ti = 64; p.Co = 256; p.To = 128; p.KWO = 3; p.lg2U = 6; p.Umask = 63;
  p.K2 = 256; conv_kernel<0, 1, false, false, true, true><<<dim3(64, 4), 256, 0, stream>>>(p);
  p.K2 = 512; conv_kernel<1, 2, false, false, true, true><<<dim3(64, 4), 256, 0, stream>>>(p);

  p.in = d1; p.w = dw1; p.bias = db1; p.out = d2; p.vidx = nullptr; p.emb = nullptr;
  p.Ci = 256; p.Ti = 128; p.Co = 128; p.To = 256; p.lg2U = 7; p.Umask = 127;
  p.K2 = 256; conv_kernel<0, 1, false, false, true, false><<<dim3(128, 2), 256, 0, stream>>>(p);
  p.K2 = 512; conv_kernel<1, 2, false, false, true, false><<<dim3(128, 2), 256, 0, stream>>>(p);

  p.in = d2; p.w = dw2; p.bias = db2; p.out = d3;
  p.Ci = 128; p.Ti = 256; p.Co = 64; p.To = 512; p.lg2U = 8; p.Umask = 255;
  p.K2 = 128; conv_kernel<0, 1, false, false, true, false><<<dim3(256, 1), 256, 0, stream>>>(p);
  p.K2 = 256; conv_kernel<1, 2, false, false, true, false><<<dim3(256, 1), 256, 0, stream>>>(p);

  p.in = d3; p.w = dw3; p.bias = db3; p.out = out;
  p.Ci = 64; p.Ti = 512; p.Co = 32; p.To = 1024; p.lg2U = 9; p.Umask = 511;
  p.K2 = 64;  conv_kernel<0, 1, false, true, false, false><<<dim3(512, 1), 256, 0, stream>>>(p);
  p.K2 = 128; conv_kernel<1, 2, false, true, false, false><<<dim3(512, 1), 256, 0, stream>>>(p);
}

// Round 4
// 1079.030 us; speedup vs baseline: 3.8050x; 1.7773x over previous
//
#include <hip/hip_runtime.h>

// ---------------------------------------------------------------------------
// VQ-VAE forward. R4: all convs/deconvs -> f16 MFMA (16x16x32, layouts
// verified by R3's vq_mfma).
//   encoder+proj: 3-pass split (A1B1+A2B1+A1B2) -> fp32-class, argmin-safe
//   decoder:      1-pass f16-hi (output tolerance 2% of absmax)
// Activations between layers: f16 hi(+lo for encoder) in NTC layout, written
// fused in the epilogue. Deconvs parity-split (even: tap k=1; odd: taps 0,2).
// VQ kernel unchanged from R3 (540us; next target).
// ---------------------------------------------------------------------------

typedef _Float16 half8 __attribute__((ext_vector_type(8)));
typedef _Float16 half4v __attribute__((ext_vector_type(4)));
typedef float f32x4 __attribute__((ext_vector_type(4)));

struct CP2 {
  const _Float16* inH; const _Float16* inL;
  const float* w; const float* bias;
  float* outF; _Float16* outH; _Float16* outL;
  const int* vidx;
  int Ci, lg2Ci, Ti, Co, To, KWO, K2, stride, pad, lg2U, Umask;
};

// SP: input splits (2=hi+lo 3-pass, 1=hi only). PAR: -1 conv, 0 deconv-even
// (tap ko=1, tin=u), 1 deconv-odd (taps ko=2*tp, tin=u+tp). GATHER: A rows
// come from e1g[vidx[..]] (dec0). OM: 0=f16 hi+lo, 1=f16 hi, 2=f32+hi+lo
// (proj), 3=f32 (final).
// Block: 256 thr = 4 waves; tile 128bt x 64co; wave 32bt x 64co; K-chunk 32.
template<int SP, int PAR, bool GATHER, bool RELU, int OM>
__global__ __launch_bounds__(256, SP == 2 ? 3 : 4) void conv_mfma(CP2 p) {
  __shared__ _Float16 As[SP * 128 * 40];
  __shared__ _Float16 Bs[SP * 64 * 40];
  const int tid = threadIdx.x;
  const int wv = tid >> 6;
  const int lane = tid & 63;
  const int m = lane & 15, q = lane >> 4;
  const int btbase = blockIdx.x * 128;
  const int cobase = blockIdx.y * 64;
  f32x4 acc[2][4];
#pragma unroll
  for (int i = 0; i < 2; ++i)
#pragma unroll
    for (int j = 0; j < 4; ++j) acc[i][j] = {0.f, 0.f, 0.f, 0.f};

  const int nkb = p.K2 >> 5;
  for (int kb = 0; kb < nkb; ++kb) {
    const int k0 = kb << 5;
    const int tap = k0 >> p.lg2Ci;
    const int ci0 = k0 & (p.Ci - 1);
    int ko, dt;
    if (PAR == 0)      { ko = 1;       dt = 0; }
    else if (PAR == 1) { ko = 2 * tap; dt = tap; }
    else               { ko = tap;     dt = tap - p.pad; }
    __syncthreads();
    // ---- stage B: 64co x 32k, gather fp32 weights + split to f16
    {
      const int cc = tid >> 2, g = tid & 3;
      const int cog = cobase + cc;
      const bool okc = cog < p.Co;
      float wvv[8];
#pragma unroll
      for (int j = 0; j < 8; ++j)
        wvv[j] = okc ? p.w[(cog * p.Ci + ci0 + g * 8 + j) * p.KWO + ko] : 0.f;
      half8 hv, lv;
#pragma unroll
      for (int j = 0; j < 8; ++j) {
        hv[j] = (_Float16)wvv[j];
        if (SP == 2) lv[j] = (_Float16)(wvv[j] - (float)hv[j]);
      }
      *(half8*)&Bs[cc * 40 + g * 8] = hv;
      if (SP == 2) *(half8*)&Bs[64 * 40 + cc * 40 + g * 8] = lv;
    }
    // ---- stage A: 128bt x 32k from f16 NTC input (b128, coalesced)
#pragma unroll
    for (int it = 0; it < 2; ++it) {
      const int r = it * 64 + (tid >> 2), g = tid & 3;
      const int bt = btbase + r;
      const int b = bt >> p.lg2U, u = bt & p.Umask;
      const int tin = (PAR < 0) ? u * p.stride + dt : u + dt;
      const bool ok = (tin >= 0) && (tin < p.Ti);
      int ai;
      if (GATHER) {
        const int er = ok ? p.vidx[b * p.Ti + tin] : 0;
        ai = er * 256 + ci0 + g * 8;
      } else {
        ai = (b * p.Ti + tin) * p.Ci + ci0 + g * 8;
      }
      const uint4 z = {0u, 0u, 0u, 0u};
      const uint4 vh = ok ? *(const uint4*)&p.inH[ai] : z;
      *(uint4*)&As[r * 40 + g * 8] = vh;
      if (SP == 2) {
        const uint4 vl = ok ? *(const uint4*)&p.inL[ai] : z;
        *(uint4*)&As[128 * 40 + r * 40 + g * 8] = vl;
      }
    }
    __syncthreads();
    // ---- MFMA
    half8 a1[2], a2[2];
#pragma unroll
    for (int rt = 0; rt < 2; ++rt) {
      const int row = wv * 32 + rt * 16 + m;
      a1[rt] = *(const half8*)&As[row * 40 + q * 8];
      if (SP == 2) a2[rt] = *(const half8*)&As[128 * 40 + row * 40 + q * 8];
    }
#pragma unroll
    for (int ct = 0; ct < 4; ++ct) {
      const half8 b1 = *(const half8*)&Bs[(ct * 16 + m) * 40 + q * 8];
      half8 b2;
      if (SP == 2) b2 = *(const half8*)&Bs[64 * 40 + (ct * 16 + m) * 40 + q * 8];
#pragma unroll
      for (int rt = 0; rt < 2; ++rt) {
        acc[rt][ct] = __builtin_amdgcn_mfma_f32_16x16x32_f16(a1[rt], b1, acc[rt][ct], 0, 0, 0);
        if (SP == 2) {
          acc[rt][ct] = __builtin_amdgcn_mfma_f32_16x16x32_f16(a2[rt], b1, acc[rt][ct], 0, 0, 0);
          acc[rt][ct] = __builtin_amdgcn_mfma_f32_16x16x32_f16(a1[rt], b2, acc[rt][ct], 0, 0, 0);
        }
      }
    }
  }
  // ---- epilogue: C layout col=lane&15, row=q*4+reg (m89-verified)
#pragma unroll
  for (int ct = 0; ct < 4; ++ct) {
    const int co = cobase + ct * 16 + m;
    if (co < p.Co) {
      const float bv = p.bias[co];
#pragma unroll
      for (int rt = 0; rt < 2; ++rt) {
#pragma unroll
        for (int j = 0; j < 4; ++j) {
          const int row = btbase + wv * 32 + rt * 16 + q * 4 + j;
          const int b = row >> p.lg2U, u = row & p.Umask;
          float v = acc[rt][ct][j] + bv;
          if (RELU) v = fmaxf(v, 0.f);
          const int t = (PAR < 0) ? u : 2 * u + PAR;
          const int oi = (b * p.To + t) * p.Co + co;
          if (OM == 3) {
            p.outF[oi] = v;
          } else if (OM == 1) {
            p.outH[oi] = (_Float16)v;
          } else {
            const _Float16 h = (_Float16)v;
            const _Float16 l = (_Float16)(v - (float)h);
            p.outH[oi] = h; p.outL[oi] = l;
            if (OM == 2) p.outF[oi] = v;
          }
        }
      }
    }
  }
}

// split fp32 -> f16 hi + f16 residual, 4 elems/thread
__global__ __launch_bounds__(256) void split_kernel(const float* __restrict__ src,
                                                    _Float16* __restrict__ hi,
                                                    _Float16* __restrict__ lo) {
  const int i = blockIdx.x * 256 + threadIdx.x;
  const float4 v = ((const float4*)src)[i];
  half4v a, b;
  a.x = (_Float16)v.x; b.x = (_Float16)(v.x - (float)a.x);
  a.y = (_Float16)v.y; b.y = (_Float16)(v.y - (float)a.y);
  a.z = (_Float16)v.z; b.z = (_Float16)(v.z - (float)a.z);
  a.w = (_Float16)v.w; b.w = (_Float16)(v.w - (float)a.w);
  ((half4v*)hi)[i] = a;
  ((half4v*)lo)[i] = b;
}

// |e_k|^2 in fp64, one wave per code.
__global__ __launch_bounds__(256) void nrm_kernel(const float* __restrict__ emb,
                                                  float* __restrict__ nrm) {
  const int k = blockIdx.x * 4 + (threadIdx.x >> 6);
  const int lane = threadIdx.x & 63;
  const float4 e4 = *(const float4*)&emb[k * 256 + lane * 4];
  double s = (double)e4.x * e4.x + (double)e4.y * e4.y +
             (double)e4.z * e4.z + (double)e4.w * e4.w;
  for (int off = 32; off; off >>= 1) s += __shfl_down(s, off);
  if (lane == 0) nrm[k] = (float)s;
}

// VQ argmin via MFMA (unchanged from R3).
__global__ __launch_bounds__(256, 3) void vq_mfma(const _Float16* __restrict__ z1g,
                                                  const _Float16* __restrict__ z2g,
                                                  const _Float16* __restrict__ e1g,
                                                  const _Float16* __restrict__ e2g,
                                                  const float* __restrict__ nrm,
                                                  float* __restrict__ pbest,
                                                  int* __restrict__ pidx) {
  __shared__ _Float16 lds[4 * 128 * 40];
  const int ZS2 = 5120, ES1 = 10240, ES2 = 15360;
  const int tid = threadIdx.x;
  const int lane = tid & 63;
  const int w = tid >> 6;
  const int m = lane & 15;
  const int q = lane >> 4;
  const int rb = blockIdx.x >> 3, seg = blockIdx.x & 7;
  const int rbase = rb * 128;
  const int w32 = w * 32;
  const int r2 = tid >> 2, s4 = tid & 3;

  float best[8]; int bk[8];
#pragma unroll
  for (int i = 0; i < 8; ++i) { best[i] = 3.4e38f; bk[i] = 0; }

  for (int cc = 0; cc < 8; ++cc) {
    const int cbase = seg * 1024 + cc * 128;
    f32x4 acc[2][8];
#pragma unroll
    for (int rt = 0; rt < 2; ++rt)
#pragma unroll
      for (int ct = 0; ct < 8; ++ct) acc[rt][ct] = {0.f, 0.f, 0.f, 0.f};

    for (int kb = 0; kb < 8; ++kb) {
      const int kof = kb * 32;
      __syncthreads();
#pragma unroll
      for (int i = 0; i < 2; ++i) {
        const int row = i * 64 + r2;
        const int zg = (rbase + row) * 256 + kof + s4 * 8;
        const int eg = (cbase + row) * 256 + kof + s4 * 8;
        const int lo = row * 40 + s4 * 8;
        *(uint4*)&lds[lo]       = *(const uint4*)&z1g[zg];
        *(uint4*)&lds[ZS2 + lo] = *(const uint4*)&z2g[zg];
        *(uint4*)&lds[ES1 + lo] = *(const uint4*)&e1g[eg];
        *(uint4*)&lds[ES2 + lo] = *(const uint4*)&e2g[eg];
      }
      __syncthreads();
      half8 a1[2], a2[2];
#pragma unroll
      for (int rt = 0; rt < 2; ++rt) {
        const int r = w32 + rt * 16 + m;
        a1[rt] = *(const half8*)&lds[r * 40 + q * 8];
        a2[rt] = *(const half8*)&lds[ZS2 + r * 40 + q * 8];
      }
#pragma unroll
      for (int ct = 0; ct < 8; ++ct) {
        const int c = ct * 16 + m;
        const half8 b1 = *(const half8*)&lds[ES1 + c * 40 + q * 8];
        const half8 b2 = *(const half8*)&lds[ES2 + c * 40 + q * 8];
#pragma unroll
        for (int rt = 0; rt < 2; ++rt) {
          acc[rt][ct] = __builtin_amdgcn_mfma_f32_16x16x32_f16(a1[rt], b1, acc[rt][ct], 0, 0, 0);
          acc[rt][ct] = __builtin_amdgcn_mfma_f32_16x16x32_f16(a2[rt], b1, acc[rt][ct], 0, 0, 0);
          acc[rt][ct] = __builtin_amdgcn_mfma_f32_16x16x32_f16(a1[rt], b2, acc[rt][ct], 0, 0, 0);
        }
      }
    }
#pragma unroll
    for (int ct = 0; ct < 8; ++ct) {
      const int k = cbase + ct * 16 + m;
      const float nv = nrm[k];
#pragma unroll
      for (int rt = 0; rt < 2; ++rt)
#pragma unroll
        for (int rg = 0; rg < 4; ++rg) {
          const float d = nv - 2.f * acc[rt][ct][rg];
          const int slot = rt * 4 + rg;
          if (d < best[slot] || (d == best[slot] && k < bk[slot])) {
            best[slot] = d; bk[slot] = k;
          }
        }
    }
  }
#pragma unroll
  for (int slot = 0; slot < 8; ++slot) {
    float bv = best[slot]; int kv = bk[slot];
    for (int off = 1; off < 16; off <<= 1) {
      const float ob = __shfl_xor(bv, off);
      const int ok = __shfl_xor(kv, off);
      if (ob < bv || (ob == bv && ok < kv)) { bv = ob; kv = ok; }
    }
    if (m == 0) {
      const int row = rbase + w32 + (slot >> 2) * 16 + q * 4 + (slot & 3);
      pbest[seg * 16384 + row] = bv;
      pidx[seg * 16384 + row] = kv;
    }
  }
}

__global__ void merge_kernel(const float* __restrict__ pbest, const int* __restrict__ pidx,
                             int* __restrict__ vidx, float* __restrict__ out_idx,
                             float* __restrict__ lacc) {
  const int n = blockIdx.x * 256 + threadIdx.x;
  float bv = pbest[n]; int kv = pidx[n];
#pragma unroll
  for (int s = 1; s < 8; ++s) {
    const float ob = pbest[s * 16384 + n];
    const int ok = pidx[s * 16384 + n];
    if (ob < bv || (ob == bv && ok < kv)) { bv = ob; kv = ok; }
  }
  vidx[n] = kv;
  out_idx[n] = (float)kv;
  if (n == 0) *lacc = 0.f;
}

__global__ __launch_bounds__(256) void loss_kernel(const float* __restrict__ zf,
                                                   const float* __restrict__ emb,
                                                   const int* __restrict__ vidx,
                                                   float* __restrict__ lacc) {
  const int e0 = (blockIdx.x * 256 + threadIdx.x) * 4;
  const int n = e0 >> 8, c = e0 & 255;
  const float4 z4 = *(const float4*)&zf[e0];
  const float4 q4 = *(const float4*)&emb[vidx[n] * 256 + c];
  const float dx = z4.x - q4.x, dy = z4.y - q4.y, dz = z4.z - q4.z, dw = z4.w - q4.w;
  float s = dx * dx + dy * dy + dz * dz + dw * dw;
  for (int off = 32; off; off >>= 1) s += __shfl_down(s, off);
  __shared__ float red[4];
  if ((threadIdx.x & 63) == 0) red[threadIdx.x >> 6] = s;
  __syncthreads();
  if (threadIdx.x == 0) atomicAdd(lacc, red[0] + red[1] + red[2] + red[3]);
}

__global__ void fin_kernel(const float* __restrict__ lacc, float* __restrict__ out, int loff) {
  if (threadIdx.x == 0) {
    const float l = *lacc * (1.f / 4194304.f);
    out[loff] = l;
    out[loff + 1] = l;
  }
}

extern "C" void kernel_launch(void* const* d_in, const int* in_sizes, int n_in,
                              void* d_out, int out_size, void* d_ws, size_t ws_size,
                              hipStream_t stream) {
  const float* x   = (const float*)d_in[0];
  const float* ew0 = (const float*)d_in[1];  const float* eb0 = (const float*)d_in[2];
  const float* ew1 = (const float*)d_in[3];  const float* eb1 = (const float*)d_in[4];
  const float* ew2 = (const float*)d_in[5];  const float* eb2 = (const float*)d_in[6];
  const float* pw  = (const float*)d_in[7];  const float* pb  = (const float*)d_in[8];
  const float* emb = (const float*)d_in[9];
  const float* dw0 = (const float*)d_in[10]; const float* db0 = (const float*)d_in[11];
  const float* dw1 = (const float*)d_in[12]; const float* db1 = (const float*)d_in[13];
  const float* dw2 = (const float*)d_in[14]; const float* db2 = (const float*)d_in[15];
  const float* dw3 = (const float*)d_in[16]; const float* db3 = (const float*)d_in[17];
  float* ws  = (float*)d_ws;
  float* out = (float*)d_out;

  // regions (float offsets), 4.19M floats each; peak ~50.4 MB
  const int A0 = 0, B0 = 4194304, C0 = 8388608, TL = 12582912;
  _Float16* xh  = (_Float16*)(ws + A0);          // x f16 (then h2, z1g/z2g, d2)
  _Float16* xl  = xh + 4194304;
  _Float16* h1h = (_Float16*)(ws + B0);          // h1 (then h3, e1g/e2g, d3)
  _Float16* h1l = h1h + 4194304;
  _Float16* h2h = (_Float16*)(ws + A0);
  _Float16* h2l = h2h + 4194304;
  _Float16* h3h = (_Float16*)(ws + B0);
  _Float16* h3l = h3h + 4194304;
  float*    zf  = ws + C0;                       // fp32 z_e (then d1)
  _Float16* z1g = (_Float16*)(ws + A0);
  _Float16* z2g = z1g + 4194304;
  _Float16* e1g = (_Float16*)(ws + B0);
  _Float16* e2g = e1g + 2097152;
  float* pbest = ws + B0 + 2097152;              // after e arrays
  int*   pidx  = (int*)(ws + B0 + 2097152 + 131072);
  _Float16* d1h = (_Float16*)(ws + C0);
  _Float16* d2h = (_Float16*)(ws + A0);
  _Float16* d3h = (_Float16*)(ws + B0);
  float* nrm  = ws + TL;
  int*   vidx = (int*)(ws + TL + 8192);
  float* lacc = ws + TL + 8192 + 16384;

  const int idx_off  = out_size - 16384;
  const int loss_off = out_size - 16386;

  // ---- encoder (3-pass f16 split MFMA) ----
  split_kernel<<<4096, 256, 0, stream>>>(x, xh, xl);

  CP2 p; p.vidx = nullptr;
  p.inH = xh; p.inL = xl; p.w = ew0; p.bias = eb0;
  p.outF = nullptr; p.outH = h1h; p.outL = h1l;
  p.Ci = 32; p.lg2Ci = 5; p.Ti = 512; p.Co = 64; p.To = 256; p.KWO = 3;
  p.K2 = 96; p.stride = 2; p.pad = 1; p.lg2U = 8; p.Umask = 255;
  conv_mfma<2, -1, false, true, 0><<<dim3(512, 1), 256, 0, stream>>>(p);

  p.inH = h1h; p.inL = h1l; p.w = ew1; p.bias = eb1; p.outH = h2h; p.outL = h2l;
  p.Ci = 64; p.lg2Ci = 6; p.Ti = 256; p.Co = 128; p.To = 128; p.K2 = 192;
  p.lg2U = 7; p.Umask = 127;
  conv_mfma<2, -1, false, true, 0><<<dim3(256, 2), 256, 0, stream>>>(p);

  p.inH = h2h; p.inL = h2l; p.w = ew2; p.bias = eb2; p.outH = h3h; p.outL = h3l;
  p.Ci = 128; p.lg2Ci = 7; p.Ti = 128; p.Co = 256; p.To = 64; p.K2 = 384;
  p.lg2U = 6; p.Umask = 63;
  conv_mfma<2, -1, false, true, 0><<<dim3(128, 4), 256, 0, stream>>>(p);

  // proj: emits zf (fp32) + z1g/z2g (f16 split) fused
  p.inH = h3h; p.inL = h3l; p.w = pw; p.bias = pb;
  p.outF = zf; p.outH = z1g; p.outL = z2g;
  p.Ci = 256; p.lg2Ci = 8; p.Ti = 64; p.Co = 256; p.To = 64; p.KWO = 1;
  p.K2 = 256; p.stride = 1; p.pad = 0; p.lg2U = 6; p.Umask = 63;
  conv_mfma<2, -1, false, false, 2><<<dim3(128, 4), 256, 0, stream>>>(p);

  // ---- VQ ----
  split_kernel<<<2048, 256, 0, stream>>>(emb, e1g, e2g);
  nrm_kernel<<<2048, 256, 0, stream>>>(emb, nrm);
  vq_mfma<<<1024, 256, 0, stream>>>(z1g, z2g, e1g, e2g, nrm, pbest, pidx);
  merge_kernel<<<64, 256, 0, stream>>>(pbest, pidx, vidx, out + idx_off, lacc);
  loss_kernel<<<4096, 256, 0, stream>>>(zf, emb, vidx, lacc);
  fin_kernel<<<1, 64, 0, stream>>>(lacc, out, loss_off);

  // ---- decoder (1-pass f16-hi MFMA; parity-split deconvs) ----
  // dec0: A = e1g[vidx] gather
  p.inH = e1g; p.inL = nullptr; p.w = dw0; p.bias = db0;
  p.outF = nullptr; p.outH = d1h; p.outL = nullptr; p.vidx = vidx;
  p.Ci = 256; p.lg2Ci = 8; p.Ti = 64; p.Co = 256; p.To = 128; p.KWO = 3;
  p.lg2U = 6; p.Umask = 63;
  p.K2 = 256; conv_mfma<1, 0, true, true, 1><<<dim3(128, 4), 256, 0, stream>>>(p);
  p.K2 = 512; conv_mfma<1, 1, true, true, 1><<<dim3(128, 4), 256, 0, stream>>>(p);

  p.inH = d1h; p.w = dw1; p.bias = db1; p.outH = d2h; p.vidx = nullptr;
  p.Ci = 256; p.lg2Ci = 8; p.Ti = 128; p.Co = 128; p.To = 256;
  p.lg2U = 7; p.Umask = 127;
  p.K2 = 256; conv_mfma<1, 0, false, true, 1><<<dim3(256, 2), 256, 0, stream>>>(p);
  p.K2 = 512; conv_mfma<1, 1, false, true, 1><<<dim3(256, 2), 256, 0, stream>>>(p);

  p.inH = d2h; p.w = dw2; p.bias = db2; p.outH = d3h;
  p.Ci = 128; p.lg2Ci = 7; p.Ti = 256; p.Co = 64; p.To = 512;
  p.lg2U = 8; p.Umask = 255;
  p.K2 = 128; conv_mfma<1, 0, false, true, 1><<<dim3(512, 1), 256, 0, stream>>>(p);
  p.K2 = 256; conv_mfma<1, 1, false, true, 1><<<dim3(512, 1), 256, 0, stream>>>(p);

  // dec3: fp32 out in (B,T,A) directly
  p.inH = d3h; p.w = dw3; p.bias = db3; p.outF = out;
  p.Ci = 64; p.lg2Ci = 6; p.Ti = 512; p.Co = 32; p.To = 1024;
  p.lg2U = 9; p.Umask = 511;
  p.K2 = 64;  conv_mfma<1, 0, false, false, 3><<<dim3(1024, 1), 256, 0, stream>>>(p);
  p.K2 = 128; conv_mfma<1, 1, false, false, 3><<<dim3(1024, 1), 256, 0, stream>>>(p);
}

// Round 5
// 945.826 us; speedup vs baseline: 4.3409x; 1.1408x over previous
//
#include <hip/hip_runtime.h>

// ---------------------------------------------------------------------------
// VQ-VAE forward. R5: vq_mfma XCD-locality round.
//  - vq grid decomposition swapped: rb = bid & 127 (so round-robin block->XCD
//    gives each XCD a 2.1 MB L2-resident z slice; the 8x z re-staging that
//    caused 770 MB of L2-miss traffic now hits L2). seg = bid >> 7.
//  - vq launch_bounds -> 4 blocks/CU (LDS 40 KB).
//  - emb split + |e|^2 norm fused into one kernel.
// Convs (f16 MFMA, R4) unchanged.
// ---------------------------------------------------------------------------

typedef _Float16 half8 __attribute__((ext_vector_type(8)));
typedef _Float16 half4v __attribute__((ext_vector_type(4)));
typedef float f32x4 __attribute__((ext_vector_type(4)));

struct CP2 {
  const _Float16* inH; const _Float16* inL;
  const float* w; const float* bias;
  float* outF; _Float16* outH; _Float16* outL;
  const int* vidx;
  int Ci, lg2Ci, Ti, Co, To, KWO, K2, stride, pad, lg2U, Umask;
};

// SP: input splits (2=hi+lo 3-pass, 1=hi only). PAR: -1 conv, 0 deconv-even
// (tap ko=1, tin=u), 1 deconv-odd (taps ko=2*tp, tin=u+tp). GATHER: A rows
// come from e1g[vidx[..]] (dec0). OM: 0=f16 hi+lo, 1=f16 hi, 2=f32+hi+lo
// (proj), 3=f32 (final).
template<int SP, int PAR, bool GATHER, bool RELU, int OM>
__global__ __launch_bounds__(256, SP == 2 ? 3 : 4) void conv_mfma(CP2 p) {
  __shared__ _Float16 As[SP * 128 * 40];
  __shared__ _Float16 Bs[SP * 64 * 40];
  const int tid = threadIdx.x;
  const int wv = tid >> 6;
  const int lane = tid & 63;
  const int m = lane & 15, q = lane >> 4;
  const int btbase = blockIdx.x * 128;
  const int cobase = blockIdx.y * 64;
  f32x4 acc[2][4];
#pragma unroll
  for (int i = 0; i < 2; ++i)
#pragma unroll
    for (int j = 0; j < 4; ++j) acc[i][j] = {0.f, 0.f, 0.f, 0.f};

  const int nkb = p.K2 >> 5;
  for (int kb = 0; kb < nkb; ++kb) {
    const int k0 = kb << 5;
    const int tap = k0 >> p.lg2Ci;
    const int ci0 = k0 & (p.Ci - 1);
    int ko, dt;
    if (PAR == 0)      { ko = 1;       dt = 0; }
    else if (PAR == 1) { ko = 2 * tap; dt = tap; }
    else               { ko = tap;     dt = tap - p.pad; }
    __syncthreads();
    {
      const int cc = tid >> 2, g = tid & 3;
      const int cog = cobase + cc;
      const bool okc = cog < p.Co;
      float wvv[8];
#pragma unroll
      for (int j = 0; j < 8; ++j)
        wvv[j] = okc ? p.w[(cog * p.Ci + ci0 + g * 8 + j) * p.KWO + ko] : 0.f;
      half8 hv, lv;
#pragma unroll
      for (int j = 0; j < 8; ++j) {
        hv[j] = (_Float16)wvv[j];
        if (SP == 2) lv[j] = (_Float16)(wvv[j] - (float)hv[j]);
      }
      *(half8*)&Bs[cc * 40 + g * 8] = hv;
      if (SP == 2) *(half8*)&Bs[64 * 40 + cc * 40 + g * 8] = lv;
    }
#pragma unroll
    for (int it = 0; it < 2; ++it) {
      const int r = it * 64 + (tid >> 2), g = tid & 3;
      const int bt = btbase + r;
      const int b = bt >> p.lg2U, u = bt & p.Umask;
      const int tin = (PAR < 0) ? u * p.stride + dt : u + dt;
      const bool ok = (tin >= 0) && (tin < p.Ti);
      int ai;
      if (GATHER) {
        const int er = ok ? p.vidx[b * p.Ti + tin] : 0;
        ai = er * 256 + ci0 + g * 8;
      } else {
        ai = (b * p.Ti + tin) * p.Ci + ci0 + g * 8;
      }
      const uint4 z = {0u, 0u, 0u, 0u};
      const uint4 vh = ok ? *(const uint4*)&p.inH[ai] : z;
      *(uint4*)&As[r * 40 + g * 8] = vh;
      if (SP == 2) {
        const uint4 vl = ok ? *(const uint4*)&p.inL[ai] : z;
        *(uint4*)&As[128 * 40 + r * 40 + g * 8] = vl;
      }
    }
    __syncthreads();
    half8 a1[2], a2[2];
#pragma unroll
    for (int rt = 0; rt < 2; ++rt) {
      const int row = wv * 32 + rt * 16 + m;
      a1[rt] = *(const half8*)&As[row * 40 + q * 8];
      if (SP == 2) a2[rt] = *(const half8*)&As[128 * 40 + row * 40 + q * 8];
    }
#pragma unroll
    for (int ct = 0; ct < 4; ++ct) {
      const half8 b1 = *(const half8*)&Bs[(ct * 16 + m) * 40 + q * 8];
      half8 b2;
      if (SP == 2) b2 = *(const half8*)&Bs[64 * 40 + (ct * 16 + m) * 40 + q * 8];
#pragma unroll
      for (int rt = 0; rt < 2; ++rt) {
        acc[rt][ct] = __builtin_amdgcn_mfma_f32_16x16x32_f16(a1[rt], b1, acc[rt][ct], 0, 0, 0);
        if (SP == 2) {
          acc[rt][ct] = __builtin_amdgcn_mfma_f32_16x16x32_f16(a2[rt], b1, acc[rt][ct], 0, 0, 0);
          acc[rt][ct] = __builtin_amdgcn_mfma_f32_16x16x32_f16(a1[rt], b2, acc[rt][ct], 0, 0, 0);
        }
      }
    }
  }
#pragma unroll
  for (int ct = 0; ct < 4; ++ct) {
    const int co = cobase + ct * 16 + m;
    if (co < p.Co) {
      const float bv = p.bias[co];
#pragma unroll
      for (int rt = 0; rt < 2; ++rt) {
#pragma unroll
        for (int j = 0; j < 4; ++j) {
          const int row = btbase + wv * 32 + rt * 16 + q * 4 + j;
          const int b = row >> p.lg2U, u = row & p.Umask;
          float v = acc[rt][ct][j] + bv;
          if (RELU) v = fmaxf(v, 0.f);
          const int t = (PAR < 0) ? u : 2 * u + PAR;
          const int oi = (b * p.To + t) * p.Co + co;
          if (OM == 3) {
            p.outF[oi] = v;
          } else if (OM == 1) {
            p.outH[oi] = (_Float16)v;
          } else {
            const _Float16 h = (_Float16)v;
            const _Float16 l = (_Float16)(v - (float)h);
            p.outH[oi] = h; p.outL[oi] = l;
            if (OM == 2) p.outF[oi] = v;
          }
        }
      }
    }
  }
}

// split fp32 -> f16 hi + f16 residual, 4 elems/thread
__global__ __launch_bounds__(256) void split_kernel(const float* __restrict__ src,
                                                    _Float16* __restrict__ hi,
                                                    _Float16* __restrict__ lo) {
  const int i = blockIdx.x * 256 + threadIdx.x;
  const float4 v = ((const float4*)src)[i];
  half4v a, b;
  a.x = (_Float16)v.x; b.x = (_Float16)(v.x - (float)a.x);
  a.y = (_Float16)v.y; b.y = (_Float16)(v.y - (float)a.y);
  a.z = (_Float16)v.z; b.z = (_Float16)(v.z - (float)a.z);
  a.w = (_Float16)v.w; b.w = (_Float16)(v.w - (float)a.w);
  ((half4v*)hi)[i] = a;
  ((half4v*)lo)[i] = b;
}

// emb: split to f16 hi/lo AND |e_k|^2 in fp64 — one wave per code, fused.
__global__ __launch_bounds__(256) void emb_prep(const float* __restrict__ emb,
                                                _Float16* __restrict__ hi,
                                                _Float16* __restrict__ lo,
                                                float* __restrict__ nrm) {
  const int k = blockIdx.x * 4 + (threadIdx.x >> 6);
  const int lane = threadIdx.x & 63;
  const int i = k * 64 + lane;
  const float4 v = ((const float4*)emb)[i];
  half4v a, b;
  a.x = (_Float16)v.x; b.x = (_Float16)(v.x - (float)a.x);
  a.y = (_Float16)v.y; b.y = (_Float16)(v.y - (float)a.y);
  a.z = (_Float16)v.z; b.z = (_Float16)(v.z - (float)a.z);
  a.w = (_Float16)v.w; b.w = (_Float16)(v.w - (float)a.w);
  ((half4v*)hi)[i] = a;
  ((half4v*)lo)[i] = b;
  double s = (double)v.x * v.x + (double)v.y * v.y +
             (double)v.z * v.z + (double)v.w * v.w;
  for (int off = 32; off; off >>= 1) s += __shfl_down(s, off);
  if (lane == 0) nrm[k] = (float)s;
}

// VQ argmin via MFMA. R5: rb = bid & 127 (round-robin block->XCD => each XCD
// holds a 2.1 MB L2-resident z slice; z re-staging hits L2 not L3).
__global__ __launch_bounds__(256, 4) void vq_mfma(const _Float16* __restrict__ z1g,
                                                  const _Float16* __restrict__ z2g,
                                                  const _Float16* __restrict__ e1g,
                                                  const _Float16* __restrict__ e2g,
                                                  const float* __restrict__ nrm,
                                                  float* __restrict__ pbest,
                                                  int* __restrict__ pidx) {
  __shared__ _Float16 lds[4 * 128 * 40];
  const int ZS2 = 5120, ES1 = 10240, ES2 = 15360;
  const int tid = threadIdx.x;
  const int lane = tid & 63;
  const int w = tid >> 6;
  const int m = lane & 15;
  const int q = lane >> 4;
  const int rb = blockIdx.x & 127, seg = blockIdx.x >> 7;   // XCD-locality swizzle
  const int rbase = rb * 128;
  const int w32 = w * 32;
  const int r2 = tid >> 2, s4 = tid & 3;

  float best[8]; int bk[8];
#pragma unroll
  for (int i = 0; i < 8; ++i) { best[i] = 3.4e38f; bk[i] = 0; }

  for (int cc = 0; cc < 8; ++cc) {
    const int cbase = seg * 1024 + cc * 128;
    f32x4 acc[2][8];
#pragma unroll
    for (int rt = 0; rt < 2; ++rt)
#pragma unroll
      for (int ct = 0; ct < 8; ++ct) acc[rt][ct] = {0.f, 0.f, 0.f, 0.f};

    for (int kb = 0; kb < 8; ++kb) {
      const int kof = kb * 32;
      __syncthreads();
#pragma unroll
      for (int i = 0; i < 2; ++i) {
        const int row = i * 64 + r2;
        const int zg = (rbase + row) * 256 + kof + s4 * 8;
        const int eg = (cbase + row) * 256 + kof + s4 * 8;
        const int lo = row * 40 + s4 * 8;
        *(uint4*)&lds[lo]       = *(const uint4*)&z1g[zg];
        *(uint4*)&lds[ZS2 + lo] = *(const uint4*)&z2g[zg];
        *(uint4*)&lds[ES1 + lo] = *(const uint4*)&e1g[eg];
        *(uint4*)&lds[ES2 + lo] = *(const uint4*)&e2g[eg];
      }
      __syncthreads();
      half8 a1[2], a2[2];
#pragma unroll
      for (int rt = 0; rt < 2; ++rt) {
        const int r = w32 + rt * 16 + m;
        a1[rt] = *(const half8*)&lds[r * 40 + q * 8];
        a2[rt] = *(const half8*)&lds[ZS2 + r * 40 + q * 8];
      }
#pragma unroll
      for (int ct = 0; ct < 8; ++ct) {
        const int c = ct * 16 + m;
        const half8 b1 = *(const half8*)&lds[ES1 + c * 40 + q * 8];
        const half8 b2 = *(const half8*)&lds[ES2 + c * 40 + q * 8];
#pragma unroll
        for (int rt = 0; rt < 2; ++rt) {
          acc[rt][ct] = __builtin_amdgcn_mfma_f32_16x16x32_f16(a1[rt], b1, acc[rt][ct], 0, 0, 0);
          acc[rt][ct] = __builtin_amdgcn_mfma_f32_16x16x32_f16(a2[rt], b1, acc[rt][ct], 0, 0, 0);
          acc[rt][ct] = __builtin_amdgcn_mfma_f32_16x16x32_f16(a1[rt], b2, acc[rt][ct], 0, 0, 0);
        }
      }
    }
#pragma unroll
    for (int ct = 0; ct < 8; ++ct) {
      const int k = cbase + ct * 16 + m;
      const float nv = nrm[k];
#pragma unroll
      for (int rt = 0; rt < 2; ++rt)
#pragma unroll
        for (int rg = 0; rg < 4; ++rg) {
          const float d = nv - 2.f * acc[rt][ct][rg];
          const int slot = rt * 4 + rg;
          if (d < best[slot] || (d == best[slot] && k < bk[slot])) {
            best[slot] = d; bk[slot] = k;
          }
        }
    }
  }
#pragma unroll
  for (int slot = 0; slot < 8; ++slot) {
    float bv = best[slot]; int kv = bk[slot];
    for (int off = 1; off < 16; off <<= 1) {
      const float ob = __shfl_xor(bv, off);
      const int ok = __shfl_xor(kv, off);
      if (ob < bv || (ob == bv && ok < kv)) { bv = ob; kv = ok; }
    }
    if (m == 0) {
      const int row = rbase + w32 + (slot >> 2) * 16 + q * 4 + (slot & 3);
      pbest[seg * 16384 + row] = bv;
      pidx[seg * 16384 + row] = kv;
    }
  }
}

__global__ void merge_kernel(const float* __restrict__ pbest, const int* __restrict__ pidx,
                             int* __restrict__ vidx, float* __restrict__ out_idx,
                             float* __restrict__ lacc) {
  const int n = blockIdx.x * 256 + threadIdx.x;
  float bv = pbest[n]; int kv = pidx[n];
#pragma unroll
  for (int s = 1; s < 8; ++s) {
    const float ob = pbest[s * 16384 + n];
    const int ok = pidx[s * 16384 + n];
    if (ob < bv || (ob == bv && ok < kv)) { bv = ob; kv = ok; }
  }
  vidx[n] = kv;
  out_idx[n] = (float)kv;
  if (n == 0) *lacc = 0.f;
}

__global__ __launch_bounds__(256) void loss_kernel(const float* __restrict__ zf,
                                                   const float* __restrict__ emb,
                                                   const int* __restrict__ vidx,
                                                   float* __restrict__ lacc) {
  const int e0 = (blockIdx.x * 256 + threadIdx.x) * 4;
  const int n = e0 >> 8, c = e0 & 255;
  const float4 z4 = *(const float4*)&zf[e0];
  const float4 q4 = *(const float4*)&emb[vidx[n] * 256 + c];
  const float dx = z4.x - q4.x, dy = z4.y - q4.y, dz = z4.z - q4.z, dw = z4.w - q4.w;
  float s = dx * dx + dy * dy + dz * dz + dw * dw;
  for (int off = 32; off; off >>= 1) s += __shfl_down(s, off);
  __shared__ float red[4];
  if ((threadIdx.x & 63) == 0) red[threadIdx.x >> 6] = s;
  __syncthreads();
  if (threadIdx.x == 0) atomicAdd(lacc, red[0] + red[1] + red[2] + red[3]);
}

__global__ void fin_kernel(const float* __restrict__ lacc, float* __restrict__ out, int loff) {
  if (threadIdx.x == 0) {
    const float l = *lacc * (1.f / 4194304.f);
    out[loff] = l;
    out[loff + 1] = l;
  }
}

extern "C" void kernel_launch(void* const* d_in, const int* in_sizes, int n_in,
                              void* d_out, int out_size, void* d_ws, size_t ws_size,
                              hipStream_t stream) {
  const float* x   = (const float*)d_in[0];
  const float* ew0 = (const float*)d_in[1];  const float* eb0 = (const float*)d_in[2];
  const float* ew1 = (const float*)d_in[3];  const float* eb1 = (const float*)d_in[4];
  const float* ew2 = (const float*)d_in[5];  const float* eb2 = (const float*)d_in[6];
  const float* pw  = (const float*)d_in[7];  const float* pb  = (const float*)d_in[8];
  const float* emb = (const float*)d_in[9];
  const float* dw0 = (const float*)d_in[10]; const float* db0 = (const float*)d_in[11];
  const float* dw1 = (const float*)d_in[12]; const float* db1 = (const float*)d_in[13];
  const float* dw2 = (const float*)d_in[14]; const float* db2 = (const float*)d_in[15];
  const float* dw3 = (const float*)d_in[16]; const float* db3 = (const float*)d_in[17];
  float* ws  = (float*)d_ws;
  float* out = (float*)d_out;

  const int A0 = 0, B0 = 4194304, C0 = 8388608, TL = 12582912;
  _Float16* xh  = (_Float16*)(ws + A0);
  _Float16* xl  = xh + 4194304;
  _Float16* h1h = (_Float16*)(ws + B0);
  _Float16* h1l = h1h + 4194304;
  _Float16* h2h = (_Float16*)(ws + A0);
  _Float16* h2l = h2h + 4194304;
  _Float16* h3h = (_Float16*)(ws + B0);
  _Float16* h3l = h3h + 4194304;
  float*    zf  = ws + C0;
  _Float16* z1g = (_Float16*)(ws + A0);
  _Float16* z2g = z1g + 4194304;
  _Float16* e1g = (_Float16*)(ws + B0);
  _Float16* e2g = e1g + 2097152;
  float* pbest = ws + B0 + 2097152;
  int*   pidx  = (int*)(ws + B0 + 2097152 + 131072);
  _Float16* d1h = (_Float16*)(ws + C0);
  _Float16* d2h = (_Float16*)(ws + A0);
  _Float16* d3h = (_Float16*)(ws + B0);
  float* nrm  = ws + TL;
  int*   vidx = (int*)(ws + TL + 8192);
  float* lacc = ws + TL + 8192 + 16384;

  const int idx_off  = out_size - 16384;
  const int loss_off = out_size - 16386;

  // ---- encoder (3-pass f16 split MFMA) ----
  split_kernel<<<4096, 256, 0, stream>>>(x, xh, xl);

  CP2 p; p.vidx = nullptr;
  p.inH = xh; p.inL = xl; p.w = ew0; p.bias = eb0;
  p.outF = nullptr; p.outH = h1h; p.outL = h1l;
  p.Ci = 32; p.lg2Ci = 5; p.Ti = 512; p.Co = 64; p.To = 256; p.KWO = 3;
  p.K2 = 96; p.stride = 2; p.pad = 1; p.lg2U = 8; p.Umask = 255;
  conv_mfma<2, -1, false, true, 0><<<dim3(512, 1), 256, 0, stream>>>(p);

  p.inH = h1h; p.inL = h1l; p.w = ew1; p.bias = eb1; p.outH = h2h; p.outL = h2l;
  p.Ci = 64; p.lg2Ci = 6; p.Ti = 256; p.Co = 128; p.To = 128; p.K2 = 192;
  p.lg2U = 7; p.Umask = 127;
  conv_mfma<2, -1, false, true, 0><<<dim3(256, 2), 256, 0, stream>>>(p);

  p.inH = h2h; p.inL = h2l; p.w = ew2; p.bias = eb2; p.outH = h3h; p.outL = h3l;
  p.Ci = 128; p.lg2Ci = 7; p.Ti = 128; p.Co = 256; p.To = 64; p.K2 = 384;
  p.lg2U = 6; p.Umask = 63;
  conv_mfma<2, -1, false, true, 0><<<dim3(128, 4), 256, 0, stream>>>(p);

  p.inH = h3h; p.inL = h3l; p.w = pw; p.bias = pb;
  p.outF = zf; p.outH = z1g; p.outL = z2g;
  p.Ci = 256; p.lg2Ci = 8; p.Ti = 64; p.Co = 256; p.To = 64; p.KWO = 1;
  p.K2 = 256; p.stride = 1; p.pad = 0; p.lg2U = 6; p.Umask = 63;
  conv_mfma<2, -1, false, false, 2><<<dim3(128, 4), 256, 0, stream>>>(p);

  // ---- VQ ----
  emb_prep<<<2048, 256, 0, stream>>>(emb, e1g, e2g, nrm);
  vq_mfma<<<1024, 256, 0, stream>>>(z1g, z2g, e1g, e2g, nrm, pbest, pidx);
  merge_kernel<<<64, 256, 0, stream>>>(pbest, pidx, vidx, out + idx_off, lacc);
  loss_kernel<<<4096, 256, 0, stream>>>(zf, emb, vidx, lacc);
  fin_kernel<<<1, 64, 0, stream>>>(lacc, out, loss_off);

  // ---- decoder (1-pass f16-hi MFMA; parity-split deconvs) ----
  p.inH = e1g; p.inL = nullptr; p.w = dw0; p.bias = db0;
  p.outF = nullptr; p.outH = d1h; p.outL = nullptr; p.vidx = vidx;
  p.Ci = 256; p.lg2Ci = 8; p.Ti = 64; p.Co = 256; p.To = 128; p.KWO = 3;
  p.lg2U = 6; p.Umask = 63;
  p.K2 = 256; conv_mfma<1, 0, true, true, 1><<<dim3(128, 4), 256, 0, stream>>>(p);
  p.K2 = 512; conv_mfma<1, 1, true, true, 1><<<dim3(128, 4), 256, 0, stream>>>(p);

  p.inH = d1h; p.w = dw1; p.bias = db1; p.outH = d2h; p.vidx = nullptr;
  p.Ci = 256; p.lg2Ci = 8; p.Ti = 128; p.Co = 128; p.To = 256;
  p.lg2U = 7; p.Umask = 127;
  p.K2 = 256; conv_mfma<1, 0, false, true, 1><<<dim3(256, 2), 256, 0, stream>>>(p);
  p.K2 = 512; conv_mfma<1, 1, false, true, 1><<<dim3(256, 2), 256, 0, stream>>>(p);

  p.inH = d2h; p.w = dw2; p.bias = db2; p.outH = d3h;
  p.Ci = 128; p.lg2Ci = 7; p.Ti = 256; p.Co = 64; p.To = 512;
  p.lg2U = 8; p.Umask = 255;
  p.K2 = 128; conv_mfma<1, 0, false, true, 1><<<dim3(512, 1), 256, 0, stream>>>(p);
  p.K2 = 256; conv_mfma<1, 1, false, true, 1><<<dim3(512, 1), 256, 0, stream>>>(p);

  p.inH = d3h; p.w = dw3; p.bias = db3; p.outF = out;
  p.Ci = 64; p.lg2Ci = 6; p.Ti = 512; p.Co = 32; p.To = 1024;
  p.lg2U = 9; p.Umask = 511;
  p.K2 = 64;  conv_mfma<1, 0, false, false, 3><<<dim3(1024, 1), 256, 0, stream>>>(p);
  p.K2 = 128; conv_mfma<1, 1, false, false, 3><<<dim3(1024, 1), 256, 0, stream>>>(p);
}